// Round 5
// baseline (568.570 us; speedup 1.0000x reference)
//
#include <hip/hip_runtime.h>

#define SCAN_B 1024

using bf16x8 = __attribute__((ext_vector_type(8))) short;
using f32x4  = __attribute__((ext_vector_type(4))) float;
typedef unsigned short ushort4v __attribute__((ext_vector_type(4)));

// split fp32 into bf16 hi (truncation) + bf16 lo (RNE of exact remainder)
__device__ inline void split1(float x, unsigned short& h, unsigned short& l) {
  unsigned u  = __float_as_uint(x);
  unsigned hu = u & 0xFFFF0000u;
  float lo = x - __uint_as_float(hu);
  unsigned lu = __float_as_uint(lo);
  h = (unsigned short)(hu >> 16);
  l = (unsigned short)((lu + 0x7FFFu + ((lu >> 16) & 1u)) >> 16);
}

// ---------------- precompute kernels ----------------

__global__ void zero2_kernel(int* __restrict__ a, int* __restrict__ b, int n) {
  int i = blockIdx.x * blockDim.x + threadIdx.x;
  if (i < n) { a[i] = 0; b[i] = 0; }
}

__global__ void count_kernel(const int* __restrict__ ei, int* __restrict__ cnt, int E) {
  int i = blockIdx.x * blockDim.x + threadIdx.x;
  if (i < E) atomicAdd(&cnt[ei[E + i]], 1);
}

__global__ void dinv_kernel(const int* __restrict__ cnt, float* __restrict__ dinv, int n) {
  int i = blockIdx.x * blockDim.x + threadIdx.x;
  if (i < n) dinv[i] = rsqrtf((float)(cnt[i] + 1));
}

// scan over (cnt[i] + 1): row length includes the appended self edge
__global__ void scan1_kernel(const int* __restrict__ cnt, int* __restrict__ rowstart,
                             int* __restrict__ bsum, int n) {
  __shared__ int sm[SCAN_B];
  const int t = threadIdx.x;
  const int i = blockIdx.x * SCAN_B + t;
  int v = (i < n) ? (cnt[i] + 1) : 0;
  sm[t] = v;
  __syncthreads();
  for (int off = 1; off < SCAN_B; off <<= 1) {
    int x = (t >= off) ? sm[t - off] : 0;
    __syncthreads();
    if (t >= off) sm[t] += x;
    __syncthreads();
  }
  if (i < n) rowstart[i] = sm[t] - v;
  if (t == SCAN_B - 1) bsum[blockIdx.x] = sm[t];
}

__global__ void scan2_kernel(int* __restrict__ bsum, int nb) {
  __shared__ int sm[SCAN_B];
  const int t = threadIdx.x;
  int v = (t < nb) ? bsum[t] : 0;
  sm[t] = v;
  __syncthreads();
  for (int off = 1; off < SCAN_B; off <<= 1) {
    int x = (t >= off) ? sm[t - off] : 0;
    __syncthreads();
    if (t >= off) sm[t] += x;
    __syncthreads();
  }
  if (t < nb) bsum[t] = sm[t] - v;
}

__global__ void scan3_kernel(int* __restrict__ rowstart, const int* __restrict__ bsum, int n) {
  int i = blockIdx.x * blockDim.x + threadIdx.x;
  if (i < n) rowstart[i] += bsum[i / SCAN_B];
}

__global__ void fill_kernel(const int* __restrict__ ei, int* __restrict__ fillc,
                            const int* __restrict__ rowstart, const float* __restrict__ dinv,
                            float2* __restrict__ ew, int E) {
  int e = blockIdx.x * blockDim.x + threadIdx.x;
  if (e < E) {
    int s = ei[e];
    int d = ei[E + e];
    int p = atomicAdd(&fillc[d], 1);
    ew[rowstart[d] + p] = make_float2(__int_as_float(s), dinv[s] * dinv[d]);
  }
}

// self edge goes in the last slot of each row: weight dinv^2
__global__ void selfedge_kernel(const int* __restrict__ rowstart, const int* __restrict__ cnt,
                                const float* __restrict__ dinv, float2* __restrict__ ew, int N) {
  int n = blockIdx.x * blockDim.x + threadIdx.x;
  if (n < N) {
    float dn = dinv[n];
    ew[rowstart[n] + cnt[n]] = make_float2(__int_as_float(n), dn * dn);
  }
}

// W [K][N] fp32 -> transposed split Wh/Wl [N][K] bf16 (k-contiguous for MFMA staging)
__global__ void wsplit_kernel(const float* __restrict__ W, unsigned short* __restrict__ Wh,
                              unsigned short* __restrict__ Wl, int K, int N) {
  int i = blockIdx.x * blockDim.x + threadIdx.x;
  if (i < K * N) {
    int k = i / N, n = i % N;
    unsigned short h, l;
    split1(W[i], h, l);
    Wh[(size_t)n * K + k] = h;
    Wl[(size_t)n * K + k] = l;
  }
}

// ---------------- split-bf16 MFMA GEMM ----------------
// C[M x N] = A[M x K] @ B[K x N], BN == N. A fp32 (split in-kernel),
// B pre-split/transposed: Wh/Wl [N][K] bf16. BK=32, 256 threads = 4 waves (2x2).
// acc = Ah*Bh + Ah*Bl + Al*Bh.  BM=64 -> 1563 blocks for latency hiding.
// Epilogue: per-wave LDS transpose so C stores are full-line dwordx4.

template <int BM, int BN>
__global__ void __launch_bounds__(256)
gemm_mfma_kernel(const float* __restrict__ A, const unsigned short* __restrict__ Wh,
                 const unsigned short* __restrict__ Wl, float* __restrict__ C,
                 int M, int K) {
  constexpr int BK    = 32;
  constexpr int LDK   = 40;             // bf16 elems per LDS row (80B)
  constexpr int MR    = BM / 2 / 16;    // 2 for BM=64
  constexpr int NR    = BN / 2 / 16;    // 4 (BN=128) or 2 (BN=64)
  constexpr int N     = BN;
  constexpr int BCOP  = (BN * 4) / 256; // B copy iters
  constexpr int APASS = BM / 32;        // A rows per thread

  __shared__ __align__(16) char smem[(size_t)(BM + BN) * LDK * 4];
  unsigned short* Ah = (unsigned short*)smem;
  unsigned short* Al = Ah + (size_t)BM * LDK;
  unsigned short* Bh = Al + (size_t)BM * LDK;
  unsigned short* Bl = Bh + (size_t)BN * LDK;

  const int tid  = threadIdx.x;
  const int lane = tid & 63;
  const int w    = tid >> 6;
  const int wm   = w >> 1;
  const int wn   = w & 1;
  const int fr   = lane & 15;
  const int fq   = lane >> 4;
  const int m0   = blockIdx.x * BM;

  const int a_c = tid & 7;     // k-chunk (4 floats)
  const int a_m = tid >> 3;    // row 0..31

  float4 av[APASS];
  uint4  bhv[BCOP], blv[BCOP];

  auto loadA = [&](int kt) {
#pragma unroll
    for (int p = 0; p < APASS; ++p) {
      const int gm = m0 + a_m + 32 * p;
      av[p] = (gm < M) ? *(const float4*)&A[(size_t)gm * K + kt + 4 * a_c]
                       : make_float4(0.f, 0.f, 0.f, 0.f);
    }
  };
  auto loadB = [&](int kt) {
#pragma unroll
    for (int i = 0; i < BCOP; ++i) {
      const int idx = tid + i * 256;
      const int r = idx >> 2, jj = idx & 3;
      bhv[i] = *(const uint4*)&Wh[(size_t)r * K + kt + 8 * jj];
      blv[i] = *(const uint4*)&Wl[(size_t)r * K + kt + 8 * jj];
    }
  };

  f32x4 acc[MR][NR] = {};

  loadA(0);
  loadB(0);

  for (int kt = 0; kt < K; kt += BK) {
    __syncthreads();   // previous tile's LDS reads complete

    // ---- regs -> LDS (A split + B copy) ----
#pragma unroll
    for (int p = 0; p < APASS; ++p) {
      const int r = a_m + 32 * p;
      ushort4v hv, lv;
      split1(av[p].x, ((unsigned short*)&hv)[0], ((unsigned short*)&lv)[0]);
      split1(av[p].y, ((unsigned short*)&hv)[1], ((unsigned short*)&lv)[1]);
      split1(av[p].z, ((unsigned short*)&hv)[2], ((unsigned short*)&lv)[2]);
      split1(av[p].w, ((unsigned short*)&hv)[3], ((unsigned short*)&lv)[3]);
      *(ushort4v*)((char*)Ah + r * (LDK * 2) + a_c * 8) = hv;
      *(ushort4v*)((char*)Al + r * (LDK * 2) + a_c * 8) = lv;
    }
#pragma unroll
    for (int i = 0; i < BCOP; ++i) {
      const int idx = tid + i * 256;
      const int r = idx >> 2, jj = idx & 3;
      *(uint4*)((char*)Bh + r * (LDK * 2) + 16 * jj) = bhv[i];
      *(uint4*)((char*)Bl + r * (LDK * 2) + 16 * jj) = blv[i];
    }
    __syncthreads();

    // ---- issue next tile's global loads; they fly under the MFMAs ----
    if (kt + BK < K) {
      loadA(kt + BK);
      loadB(kt + BK);
    }

    // ---- fragments + MFMA ----
    bf16x8 ah[MR], al[MR], bh[NR], bl[NR];
#pragma unroll
    for (int mi = 0; mi < MR; ++mi) {
      const int r = wm * MR * 16 + mi * 16 + fr;
      ah[mi] = *(const bf16x8*)((const char*)Ah + r * (LDK * 2) + fq * 16);
      al[mi] = *(const bf16x8*)((const char*)Al + r * (LDK * 2) + fq * 16);
    }
#pragma unroll
    for (int ni = 0; ni < NR; ++ni) {
      const int r = wn * NR * 16 + ni * 16 + fr;
      bh[ni] = *(const bf16x8*)((const char*)Bh + r * (LDK * 2) + fq * 16);
      bl[ni] = *(const bf16x8*)((const char*)Bl + r * (LDK * 2) + fq * 16);
    }
#pragma unroll
    for (int mi = 0; mi < MR; ++mi)
#pragma unroll
      for (int ni = 0; ni < NR; ++ni) {
        acc[mi][ni] = __builtin_amdgcn_mfma_f32_16x16x32_bf16(ah[mi], bh[ni], acc[mi][ni], 0, 0, 0);
        acc[mi][ni] = __builtin_amdgcn_mfma_f32_16x16x32_bf16(ah[mi], bl[ni], acc[mi][ni], 0, 0, 0);
        acc[mi][ni] = __builtin_amdgcn_mfma_f32_16x16x32_bf16(al[mi], bh[ni], acc[mi][ni], 0, 0, 0);
      }
  }

  // ---- epilogue: wave-local LDS transpose -> full-line dwordx4 stores ----
  __syncthreads();   // all LDS frag reads done; safe to reuse smem

  if constexpr (NR == 4) {
    // per-wave patch [16][68] f32; one mi block (16 rows x 64 cols) at a time
    float* cst = (float*)smem + (size_t)w * (16 * 68);
#pragma unroll
    for (int mi = 0; mi < MR; ++mi) {
#pragma unroll
      for (int ni = 0; ni < NR; ++ni)
#pragma unroll
        for (int r = 0; r < 4; ++r)
          cst[(fq * 4 + r) * 68 + ni * 16 + fr] = acc[mi][ni][r];
      // 4 passes: 4 rows x 16 chunks of float4
#pragma unroll
      for (int q = 0; q < 4; ++q) {
        const int row = q * 4 + (lane >> 4);
        const int ch  = lane & 15;
        const int gm  = m0 + wm * MR * 16 + mi * 16 + row;
        float4 v = *(const float4*)&cst[row * 68 + ch * 4];
        if (gm < M) *(float4*)&C[(size_t)gm * N + wn * 64 + ch * 4] = v;
      }
    }
  } else {
    // NR == 2: per-wave patch [32][36] f32; both mi blocks (32 rows x 32 cols)
    float* cst = (float*)smem + (size_t)w * (32 * 36);
#pragma unroll
    for (int mi = 0; mi < MR; ++mi)
#pragma unroll
      for (int ni = 0; ni < NR; ++ni)
#pragma unroll
        for (int r = 0; r < 4; ++r)
          cst[(mi * 16 + fq * 4 + r) * 36 + ni * 16 + fr] = acc[mi][ni][r];
#pragma unroll
    for (int q = 0; q < 4; ++q) {
      const int row = q * 8 + (lane >> 3);
      const int ch  = lane & 7;
      const int gm  = m0 + wm * MR * 16 + row;
      float4 v = *(const float4*)&cst[row * 36 + ch * 4];
      if (gm < M) *(float4*)&C[(size_t)gm * N + wn * 32 + ch * 4] = v;
    }
  }
}

// ---------------- CSR pull aggregation: float4/lane, multi-edge per wave ----------------

template <int F>
__global__ void agg_kernel(const float* __restrict__ hin, const int* __restrict__ rowstart,
                           const int* __restrict__ cnt, const float2* __restrict__ ew,
                           const float* __restrict__ bias, float* __restrict__ outp, int N) {
  constexpr int LPE = F / 4;    // lanes per edge (float4 each)
  constexpr int EPW = 64 / LPE; // edge slots per wave
  const int wave = (int)((blockIdx.x * (size_t)blockDim.x + threadIdx.x) >> 6);
  if (wave >= N) return;
  const int lane = threadIdx.x & 63;
  const int sub  = lane / LPE;
  const int c    = lane % LPE;
  const int n    = wave;

  const int beg = rowstart[n];
  const int end = beg + cnt[n] + 1;   // incl. self edge

  float ax = 0.f, ay = 0.f, az = 0.f, aw = 0.f;
  int j = beg + sub;
  for (; j + EPW < end; j += 2 * EPW) {
    const float2 e0 = ew[j];
    const float2 e1 = ew[j + EPW];
    const float4 v0 = *(const float4*)&hin[(size_t)__float_as_int(e0.x) * F + c * 4];
    const float4 v1 = *(const float4*)&hin[(size_t)__float_as_int(e1.x) * F + c * 4];
    ax = fmaf(v0.x, e0.y, ax); ay = fmaf(v0.y, e0.y, ay);
    az = fmaf(v0.z, e0.y, az); aw = fmaf(v0.w, e0.y, aw);
    ax = fmaf(v1.x, e1.y, ax); ay = fmaf(v1.y, e1.y, ay);
    az = fmaf(v1.z, e1.y, az); aw = fmaf(v1.w, e1.y, aw);
  }
  if (j < end) {
    const float2 e = ew[j];
    const float4 v = *(const float4*)&hin[(size_t)__float_as_int(e.x) * F + c * 4];
    ax = fmaf(v.x, e.y, ax); ay = fmaf(v.y, e.y, ay);
    az = fmaf(v.z, e.y, az); aw = fmaf(v.w, e.y, aw);
  }

#pragma unroll
  for (int d = LPE; d < 64; d <<= 1) {
    ax += __shfl_xor(ax, d);
    ay += __shfl_xor(ay, d);
    az += __shfl_xor(az, d);
    aw += __shfl_xor(aw, d);
  }

  if (lane < LPE) {
    const float4 bb = *(const float4*)&bias[c * 4];
    float4 r;
    r.x = fmaxf(ax + bb.x, 0.f);
    r.y = fmaxf(ay + bb.y, 0.f);
    r.z = fmaxf(az + bb.z, 0.f);
    r.w = fmaxf(aw + bb.w, 0.f);
    *(float4*)&outp[(size_t)n * F + c * 4] = r;
  }
}

// ---------------- launch ----------------

extern "C" void kernel_launch(void* const* d_in, const int* in_sizes, int n_in,
                              void* d_out, int out_size, void* d_ws, size_t ws_size,
                              hipStream_t stream) {
  const float* x  = (const float*)d_in[0];
  const int*   ei = (const int*)d_in[1];
  const float* W1 = (const float*)d_in[2];
  const float* b1 = (const float*)d_in[3];
  const float* W2 = (const float*)d_in[4];
  const float* b2 = (const float*)d_in[5];
  float* out = (float*)d_out;

  const int F1 = in_sizes[3];           // 128
  const int F2 = in_sizes[5];           // 64
  const int F0 = in_sizes[2] / F1;      // 512
  const int N  = in_sizes[0] / F0;      // 100000
  const int E  = in_sizes[1] / 2;       // 1600000

  char* ws = (char*)d_ws;
  size_t off = 0;
  auto alloc = [&](size_t bytes) -> void* {
    void* p = ws + off;
    off = (off + bytes + 255) & ~(size_t)255;
    return p;
  };

  int*    cnt      = (int*)alloc((size_t)N * 4);
  int*    fillc    = (int*)alloc((size_t)N * 4);
  int*    rowstart = (int*)alloc((size_t)N * 4);
  float*  dinv     = (float*)alloc((size_t)N * 4);
  const int nb     = (N + SCAN_B - 1) / SCAN_B;
  int*    bsum     = (int*)alloc((size_t)nb * 4);
  float2* ew       = (float2*)alloc(((size_t)E + N) * 8);
  float*  h        = (float*)alloc((size_t)N * F1 * 4);
  float*  h1       = (float*)alloc((size_t)N * F1 * 4);
  float*  h2       = h;  // reuse
  unsigned short* W1h = (unsigned short*)alloc((size_t)F0 * F1 * 2);
  unsigned short* W1l = (unsigned short*)alloc((size_t)F0 * F1 * 2);
  unsigned short* W2h = (unsigned short*)alloc((size_t)F1 * F2 * 2);
  unsigned short* W2l = (unsigned short*)alloc((size_t)F1 * F2 * 2);

  zero2_kernel<<<(N + 255) / 256, 256, 0, stream>>>(cnt, fillc, N);
  count_kernel<<<(E + 255) / 256, 256, 0, stream>>>(ei, cnt, E);
  dinv_kernel<<<(N + 255) / 256, 256, 0, stream>>>(cnt, dinv, N);
  scan1_kernel<<<nb, SCAN_B, 0, stream>>>(cnt, rowstart, bsum, N);
  scan2_kernel<<<1, SCAN_B, 0, stream>>>(bsum, nb);
  scan3_kernel<<<(N + 255) / 256, 256, 0, stream>>>(rowstart, bsum, N);
  fill_kernel<<<(E + 255) / 256, 256, 0, stream>>>(ei, fillc, rowstart, dinv, ew, E);
  selfedge_kernel<<<(N + 255) / 256, 256, 0, stream>>>(rowstart, cnt, dinv, ew, N);
  wsplit_kernel<<<(F0 * F1 + 255) / 256, 256, 0, stream>>>(W1, W1h, W1l, F0, F1);
  wsplit_kernel<<<(F1 * F2 + 255) / 256, 256, 0, stream>>>(W2, W2h, W2l, F1, F2);

  // layer 1: h = x@W1 ; h1 = relu(agg(h) + b1)
  gemm_mfma_kernel<64, 128><<<(N + 63) / 64, 256, 0, stream>>>(x, W1h, W1l, h, N, F0);
  {
    const long blocks = ((long)N * 64 + 255) / 256;
    agg_kernel<128><<<(int)blocks, 256, 0, stream>>>(h, rowstart, cnt, ew, b1, h1, N);
  }

  // layer 2: h2 = h1@W2 ; out = relu(agg(h2) + b2)
  gemm_mfma_kernel<64, 64><<<(N + 63) / 64, 256, 0, stream>>>(h1, W2h, W2l, h2, N, F1);
  {
    const long blocks = ((long)N * 64 + 255) / 256;
    agg_kernel<64><<<(int)blocks, 256, 0, stream>>>(h2, rowstart, cnt, ew, b2, out, N);
  }
}

// Round 6
// 558.221 us; speedup vs baseline: 1.0185x; 1.0185x over previous
//
#include <hip/hip_runtime.h>

#define SCAN_B 1024

using bf16x8 = __attribute__((ext_vector_type(8))) short;
using f32x4  = __attribute__((ext_vector_type(4))) float;
typedef unsigned short ushort4v __attribute__((ext_vector_type(4)));

// split fp32 into bf16 hi (truncation) + bf16 lo (RNE of exact remainder)
__device__ inline void split1(float x, unsigned short& h, unsigned short& l) {
  unsigned u  = __float_as_uint(x);
  unsigned hu = u & 0xFFFF0000u;
  float lo = x - __uint_as_float(hu);
  unsigned lu = __float_as_uint(lo);
  h = (unsigned short)(hu >> 16);
  l = (unsigned short)((lu + 0x7FFFu + ((lu >> 16) & 1u)) >> 16);
}

// ---------------- precompute kernels ----------------

__global__ void zero2_kernel(int* __restrict__ a, int* __restrict__ b, int n) {
  int i = blockIdx.x * blockDim.x + threadIdx.x;
  if (i < n) { a[i] = 0; b[i] = 0; }
}

__global__ void count_kernel(const int* __restrict__ ei, int* __restrict__ cnt, int E) {
  int i = blockIdx.x * blockDim.x + threadIdx.x;
  if (i < E) atomicAdd(&cnt[ei[E + i]], 1);
}

__global__ void dinv_kernel(const int* __restrict__ cnt, float* __restrict__ dinv, int n) {
  int i = blockIdx.x * blockDim.x + threadIdx.x;
  if (i < n) dinv[i] = rsqrtf((float)(cnt[i] + 1));
}

// scan over (cnt[i] + 1): row length includes the appended self edge
__global__ void scan1_kernel(const int* __restrict__ cnt, int* __restrict__ rowstart,
                             int* __restrict__ bsum, int n) {
  __shared__ int sm[SCAN_B];
  const int t = threadIdx.x;
  const int i = blockIdx.x * SCAN_B + t;
  int v = (i < n) ? (cnt[i] + 1) : 0;
  sm[t] = v;
  __syncthreads();
  for (int off = 1; off < SCAN_B; off <<= 1) {
    int x = (t >= off) ? sm[t - off] : 0;
    __syncthreads();
    if (t >= off) sm[t] += x;
    __syncthreads();
  }
  if (i < n) rowstart[i] = sm[t] - v;
  if (t == SCAN_B - 1) bsum[blockIdx.x] = sm[t];
}

__global__ void scan2_kernel(int* __restrict__ bsum, int nb) {
  __shared__ int sm[SCAN_B];
  const int t = threadIdx.x;
  int v = (t < nb) ? bsum[t] : 0;
  sm[t] = v;
  __syncthreads();
  for (int off = 1; off < SCAN_B; off <<= 1) {
    int x = (t >= off) ? sm[t - off] : 0;
    __syncthreads();
    if (t >= off) sm[t] += x;
    __syncthreads();
  }
  if (t < nb) bsum[t] = sm[t] - v;
}

__global__ void scan3_kernel(int* __restrict__ rowstart, const int* __restrict__ bsum, int n) {
  int i = blockIdx.x * blockDim.x + threadIdx.x;
  if (i < n) rowstart[i] += bsum[i / SCAN_B];
}

__global__ void fill_kernel(const int* __restrict__ ei, int* __restrict__ fillc,
                            const int* __restrict__ rowstart, const float* __restrict__ dinv,
                            float2* __restrict__ ew, int E) {
  int e = blockIdx.x * blockDim.x + threadIdx.x;
  if (e < E) {
    int s = ei[e];
    int d = ei[E + e];
    int p = atomicAdd(&fillc[d], 1);
    ew[rowstart[d] + p] = make_float2(__int_as_float(s), dinv[s] * dinv[d]);
  }
}

// self edge goes in the last slot of each row: weight dinv^2
__global__ void selfedge_kernel(const int* __restrict__ rowstart, const int* __restrict__ cnt,
                                const float* __restrict__ dinv, float2* __restrict__ ew, int N) {
  int n = blockIdx.x * blockDim.x + threadIdx.x;
  if (n < N) {
    float dn = dinv[n];
    ew[rowstart[n] + cnt[n]] = make_float2(__int_as_float(n), dn * dn);
  }
}

// W [K][N] fp32 -> transposed split Wh/Wl [N][K] bf16 (k-contiguous)
__global__ void wsplit_kernel(const float* __restrict__ W, unsigned short* __restrict__ Wh,
                              unsigned short* __restrict__ Wl, int K, int N) {
  int i = blockIdx.x * blockDim.x + threadIdx.x;
  if (i < K * N) {
    int k = i / N, n = i % N;
    unsigned short h, l;
    split1(W[i], h, l);
    Wh[(size_t)n * K + k] = h;
    Wl[(size_t)n * K + k] = l;
  }
}

// ---------------- split-bf16 MFMA GEMM, A-only LDS, B direct from L2 ----------------
// C[M x N] = A[M x K] @ B[K x N], BN == N. A fp32 (split in-kernel to LDS),
// B pre-split/transposed Wh/Wl [N][K] bf16, read per-fragment from global (L2-resident,
// shared by all blocks). acc = Ah*Bh + Ah*Bl + Al*Bh. BK=32, 256 thr = 4 waves (2x2).
// Epilogue: per-wave LDS transpose (reusing A LDS) -> full-line float4 stores.
// __launch_bounds__(256,4): pin the <=128-VGPR / 16-waves-per-CU tier (r5 spilled at 8-wave tier).

template <int BM, int BN>
__global__ void __launch_bounds__(256, 4)
gemm_mfma_kernel(const float* __restrict__ A, const unsigned short* __restrict__ Wh,
                 const unsigned short* __restrict__ Wl, float* __restrict__ C,
                 int M, int K) {
  constexpr int BK    = 32;
  constexpr int LDK   = 40;             // bf16 elems per LDS row (80B)
  constexpr int MR    = BM / 2 / 16;    // 4 for BM=128
  constexpr int NR    = BN / 2 / 16;    // 4 (BN=128) or 2 (BN=64)
  constexpr int N     = BN;
  constexpr int APASS = BM / 32;
  constexpr int LDC   = NR * 16 + 4;    // epilogue patch row stride (floats)
  constexpr int SMA   = BM * LDK * 4;   // Ah+Al bytes
  constexpr int SME   = 4 * 16 * LDC * 4;
  constexpr int SMEM  = SMA > SME ? SMA : SME;

  __shared__ __align__(16) char smem[SMEM];
  unsigned short* Ah = (unsigned short*)smem;
  unsigned short* Al = Ah + (size_t)BM * LDK;

  const int tid  = threadIdx.x;
  const int lane = tid & 63;
  const int w    = tid >> 6;
  const int wm   = w >> 1;
  const int wn   = w & 1;
  const int fr   = lane & 15;
  const int fq   = lane >> 4;
  const int m0   = blockIdx.x * BM;

  const int a_c = tid & 7;     // k-chunk (4 floats)
  const int a_m = tid >> 3;    // row 0..31

  f32x4 acc[MR][NR] = {};

  for (int kt = 0; kt < K; kt += BK) {
    // ---- A global loads (consumed at split below) ----
    float4 av[APASS];
#pragma unroll
    for (int p = 0; p < APASS; ++p) {
      const int gm = m0 + a_m + 32 * p;
      av[p] = (gm < M) ? *(const float4*)&A[(size_t)gm * K + kt + 4 * a_c]
                       : make_float4(0.f, 0.f, 0.f, 0.f);
    }

    // ---- B fragment loads from global (L2); latency hides under A staging ----
    bf16x8 bh[NR], bl[NR];
#pragma unroll
    for (int ni = 0; ni < NR; ++ni) {
      const size_t r = wn * (NR * 16) + ni * 16 + fr;
      bh[ni] = *(const bf16x8*)&Wh[r * K + kt + fq * 8];
      bl[ni] = *(const bf16x8*)&Wl[r * K + kt + fq * 8];
    }

    __syncthreads();   // previous tile's LDS frag reads complete

    // ---- A: split + store to LDS ----
#pragma unroll
    for (int p = 0; p < APASS; ++p) {
      const int r = a_m + 32 * p;
      ushort4v hv, lv;
      split1(av[p].x, ((unsigned short*)&hv)[0], ((unsigned short*)&lv)[0]);
      split1(av[p].y, ((unsigned short*)&hv)[1], ((unsigned short*)&lv)[1]);
      split1(av[p].z, ((unsigned short*)&hv)[2], ((unsigned short*)&lv)[2]);
      split1(av[p].w, ((unsigned short*)&hv)[3], ((unsigned short*)&lv)[3]);
      *(ushort4v*)((char*)Ah + r * (LDK * 2) + a_c * 8) = hv;
      *(ushort4v*)((char*)Al + r * (LDK * 2) + a_c * 8) = lv;
    }
    __syncthreads();

    // ---- A frags from LDS + MFMA ----
#pragma unroll
    for (int mi = 0; mi < MR; ++mi) {
      const int rr = wm * (MR * 16) + mi * 16 + fr;
      bf16x8 ah = *(const bf16x8*)((const char*)Ah + rr * (LDK * 2) + fq * 16);
      bf16x8 al = *(const bf16x8*)((const char*)Al + rr * (LDK * 2) + fq * 16);
#pragma unroll
      for (int ni = 0; ni < NR; ++ni) {
        acc[mi][ni] = __builtin_amdgcn_mfma_f32_16x16x32_bf16(ah, bh[ni], acc[mi][ni], 0, 0, 0);
        acc[mi][ni] = __builtin_amdgcn_mfma_f32_16x16x32_bf16(ah, bl[ni], acc[mi][ni], 0, 0, 0);
        acc[mi][ni] = __builtin_amdgcn_mfma_f32_16x16x32_bf16(al, bh[ni], acc[mi][ni], 0, 0, 0);
      }
    }
  }

  // ---- epilogue: wave-local LDS transpose -> full-line float4 stores ----
  __syncthreads();   // all frag reads done; safe to reuse smem
  {
    float* cst = (float*)smem + (size_t)w * (16 * LDC);
    constexpr int CPR   = NR * 4;            // float4 chunks per row
    constexpr int EPASS = 16 * CPR / 64;
#pragma unroll
    for (int mi = 0; mi < MR; ++mi) {
#pragma unroll
      for (int ni = 0; ni < NR; ++ni)
#pragma unroll
        for (int r = 0; r < 4; ++r)
          cst[(fq * 4 + r) * LDC + ni * 16 + fr] = acc[mi][ni][r];
#pragma unroll
      for (int p = 0; p < EPASS; ++p) {
        const int idx = p * 64 + lane;
        const int row = idx / CPR;
        const int ch  = idx % CPR;
        const int gm  = m0 + wm * (MR * 16) + mi * 16 + row;
        float4 v = *(const float4*)&cst[row * LDC + ch * 4];
        if (gm < M) *(float4*)&C[(size_t)gm * N + wn * (NR * 16) + ch * 4] = v;
      }
    }
  }
}

// ---------------- CSR pull aggregation: float4/lane, multi-edge per wave ----------------

template <int F>
__global__ void agg_kernel(const float* __restrict__ hin, const int* __restrict__ rowstart,
                           const int* __restrict__ cnt, const float2* __restrict__ ew,
                           const float* __restrict__ bias, float* __restrict__ outp, int N) {
  constexpr int LPE = F / 4;    // lanes per edge (float4 each)
  constexpr int EPW = 64 / LPE; // edge slots per wave
  const int wave = (int)((blockIdx.x * (size_t)blockDim.x + threadIdx.x) >> 6);
  if (wave >= N) return;
  const int lane = threadIdx.x & 63;
  const int sub  = lane / LPE;
  const int c    = lane % LPE;
  const int n    = wave;

  const int beg = rowstart[n];
  const int end = beg + cnt[n] + 1;   // incl. self edge

  float ax = 0.f, ay = 0.f, az = 0.f, aw = 0.f;
  int j = beg + sub;
  for (; j + EPW < end; j += 2 * EPW) {
    const float2 e0 = ew[j];
    const float2 e1 = ew[j + EPW];
    const float4 v0 = *(const float4*)&hin[(size_t)__float_as_int(e0.x) * F + c * 4];
    const float4 v1 = *(const float4*)&hin[(size_t)__float_as_int(e1.x) * F + c * 4];
    ax = fmaf(v0.x, e0.y, ax); ay = fmaf(v0.y, e0.y, ay);
    az = fmaf(v0.z, e0.y, az); aw = fmaf(v0.w, e0.y, aw);
    ax = fmaf(v1.x, e1.y, ax); ay = fmaf(v1.y, e1.y, ay);
    az = fmaf(v1.z, e1.y, az); aw = fmaf(v1.w, e1.y, aw);
  }
  if (j < end) {
    const float2 e = ew[j];
    const float4 v = *(const float4*)&hin[(size_t)__float_as_int(e.x) * F + c * 4];
    ax = fmaf(v.x, e.y, ax); ay = fmaf(v.y, e.y, ay);
    az = fmaf(v.z, e.y, az); aw = fmaf(v.w, e.y, aw);
  }

#pragma unroll
  for (int d = LPE; d < 64; d <<= 1) {
    ax += __shfl_xor(ax, d);
    ay += __shfl_xor(ay, d);
    az += __shfl_xor(az, d);
    aw += __shfl_xor(aw, d);
  }

  if (lane < LPE) {
    const float4 bb = *(const float4*)&bias[c * 4];
    float4 r;
    r.x = fmaxf(ax + bb.x, 0.f);
    r.y = fmaxf(ay + bb.y, 0.f);
    r.z = fmaxf(az + bb.z, 0.f);
    r.w = fmaxf(aw + bb.w, 0.f);
    *(float4*)&outp[(size_t)n * F + c * 4] = r;
  }
}

// ---------------- launch ----------------

extern "C" void kernel_launch(void* const* d_in, const int* in_sizes, int n_in,
                              void* d_out, int out_size, void* d_ws, size_t ws_size,
                              hipStream_t stream) {
  const float* x  = (const float*)d_in[0];
  const int*   ei = (const int*)d_in[1];
  const float* W1 = (const float*)d_in[2];
  const float* b1 = (const float*)d_in[3];
  const float* W2 = (const float*)d_in[4];
  const float* b2 = (const float*)d_in[5];
  float* out = (float*)d_out;

  const int F1 = in_sizes[3];           // 128
  const int F2 = in_sizes[5];           // 64
  const int F0 = in_sizes[2] / F1;      // 512
  const int N  = in_sizes[0] / F0;      // 100000
  const int E  = in_sizes[1] / 2;       // 1600000

  char* ws = (char*)d_ws;
  size_t off = 0;
  auto alloc = [&](size_t bytes) -> void* {
    void* p = ws + off;
    off = (off + bytes + 255) & ~(size_t)255;
    return p;
  };

  int*    cnt      = (int*)alloc((size_t)N * 4);
  int*    fillc    = (int*)alloc((size_t)N * 4);
  int*    rowstart = (int*)alloc((size_t)N * 4);
  float*  dinv     = (float*)alloc((size_t)N * 4);
  const int nb     = (N + SCAN_B - 1) / SCAN_B;
  int*    bsum     = (int*)alloc((size_t)nb * 4);
  float2* ew       = (float2*)alloc(((size_t)E + N) * 8);
  float*  h        = (float*)alloc((size_t)N * F1 * 4);
  float*  h1       = (float*)alloc((size_t)N * F1 * 4);
  float*  h2       = h;  // reuse
  unsigned short* W1h = (unsigned short*)alloc((size_t)F0 * F1 * 2);
  unsigned short* W1l = (unsigned short*)alloc((size_t)F0 * F1 * 2);
  unsigned short* W2h = (unsigned short*)alloc((size_t)F1 * F2 * 2);
  unsigned short* W2l = (unsigned short*)alloc((size_t)F1 * F2 * 2);

  zero2_kernel<<<(N + 255) / 256, 256, 0, stream>>>(cnt, fillc, N);
  count_kernel<<<(E + 255) / 256, 256, 0, stream>>>(ei, cnt, E);
  dinv_kernel<<<(N + 255) / 256, 256, 0, stream>>>(cnt, dinv, N);
  scan1_kernel<<<nb, SCAN_B, 0, stream>>>(cnt, rowstart, bsum, N);
  scan2_kernel<<<1, SCAN_B, 0, stream>>>(bsum, nb);
  scan3_kernel<<<(N + 255) / 256, 256, 0, stream>>>(rowstart, bsum, N);
  fill_kernel<<<(E + 255) / 256, 256, 0, stream>>>(ei, fillc, rowstart, dinv, ew, E);
  selfedge_kernel<<<(N + 255) / 256, 256, 0, stream>>>(rowstart, cnt, dinv, ew, N);
  wsplit_kernel<<<(F0 * F1 + 255) / 256, 256, 0, stream>>>(W1, W1h, W1l, F0, F1);
  wsplit_kernel<<<(F1 * F2 + 255) / 256, 256, 0, stream>>>(W2, W2h, W2l, F1, F2);

  // layer 1: h = x@W1 ; h1 = relu(agg(h) + b1)
  gemm_mfma_kernel<128, 128><<<(N + 127) / 128, 256, 0, stream>>>(x, W1h, W1l, h, N, F0);
  {
    const long blocks = ((long)N * 64 + 255) / 256;
    agg_kernel<128><<<(int)blocks, 256, 0, stream>>>(h, rowstart, cnt, ew, b1, h1, N);
  }

  // layer 2: h2 = h1@W2 ; out = relu(agg(h2) + b2)
  gemm_mfma_kernel<128, 64><<<(N + 127) / 128, 256, 0, stream>>>(h1, W2h, W2l, h2, N, F1);
  {
    const long blocks = ((long)N * 64 + 255) / 256;
    agg_kernel<64><<<(int)blocks, 256, 0, stream>>>(h2, rowstart, cnt, ew, b2, out, N);
  }
}

// Round 7
// 452.491 us; speedup vs baseline: 1.2565x; 1.2337x over previous
//
#include <hip/hip_runtime.h>

#define SCAN_B 1024

using bf16x8 = __attribute__((ext_vector_type(8))) short;
using f32x4  = __attribute__((ext_vector_type(4))) float;
typedef unsigned short ushort4v __attribute__((ext_vector_type(4)));

// split fp32 into bf16 hi (truncation) + bf16 lo (RNE of exact remainder)
__device__ inline void split1(float x, unsigned short& h, unsigned short& l) {
  unsigned u  = __float_as_uint(x);
  unsigned hu = u & 0xFFFF0000u;
  float lo = x - __uint_as_float(hu);
  unsigned lu = __float_as_uint(lo);
  h = (unsigned short)(hu >> 16);
  l = (unsigned short)((lu + 0x7FFFu + ((lu >> 16) & 1u)) >> 16);
}

// ---------------- precompute kernels ----------------

__global__ void zero2_kernel(int* __restrict__ a, int* __restrict__ b, int n) {
  int i = blockIdx.x * blockDim.x + threadIdx.x;
  if (i < n) { a[i] = 0; b[i] = 0; }
}

__global__ void count_kernel(const int* __restrict__ ei, int* __restrict__ cnt, int E) {
  int i = blockIdx.x * blockDim.x + threadIdx.x;
  if (i < E) atomicAdd(&cnt[ei[E + i]], 1);
}

__global__ void dinv_kernel(const int* __restrict__ cnt, float* __restrict__ dinv, int n) {
  int i = blockIdx.x * blockDim.x + threadIdx.x;
  if (i < n) dinv[i] = rsqrtf((float)(cnt[i] + 1));
}

// scan over (cnt[i] + 1): row length includes the appended self edge
__global__ void scan1_kernel(const int* __restrict__ cnt, int* __restrict__ rowstart,
                             int* __restrict__ bsum, int n) {
  __shared__ int sm[SCAN_B];
  const int t = threadIdx.x;
  const int i = blockIdx.x * SCAN_B + t;
  int v = (i < n) ? (cnt[i] + 1) : 0;
  sm[t] = v;
  __syncthreads();
  for (int off = 1; off < SCAN_B; off <<= 1) {
    int x = (t >= off) ? sm[t - off] : 0;
    __syncthreads();
    if (t >= off) sm[t] += x;
    __syncthreads();
  }
  if (i < n) rowstart[i] = sm[t] - v;
  if (t == SCAN_B - 1) bsum[blockIdx.x] = sm[t];
}

__global__ void scan2_kernel(int* __restrict__ bsum, int nb) {
  __shared__ int sm[SCAN_B];
  const int t = threadIdx.x;
  int v = (t < nb) ? bsum[t] : 0;
  sm[t] = v;
  __syncthreads();
  for (int off = 1; off < SCAN_B; off <<= 1) {
    int x = (t >= off) ? sm[t - off] : 0;
    __syncthreads();
    if (t >= off) sm[t] += x;
    __syncthreads();
  }
  if (t < nb) bsum[t] = sm[t] - v;
}

__global__ void scan3_kernel(int* __restrict__ rowstart, const int* __restrict__ bsum, int n) {
  int i = blockIdx.x * blockDim.x + threadIdx.x;
  if (i < n) rowstart[i] += bsum[i / SCAN_B];
}

__global__ void fill_kernel(const int* __restrict__ ei, int* __restrict__ fillc,
                            const int* __restrict__ rowstart, const float* __restrict__ dinv,
                            float2* __restrict__ ew, int E) {
  int e = blockIdx.x * blockDim.x + threadIdx.x;
  if (e < E) {
    int s = ei[e];
    int d = ei[E + e];
    int p = atomicAdd(&fillc[d], 1);
    ew[rowstart[d] + p] = make_float2(__int_as_float(s), dinv[s] * dinv[d]);
  }
}

// self edge goes in the last slot of each row: weight dinv^2
__global__ void selfedge_kernel(const int* __restrict__ rowstart, const int* __restrict__ cnt,
                                const float* __restrict__ dinv, float2* __restrict__ ew, int N) {
  int n = blockIdx.x * blockDim.x + threadIdx.x;
  if (n < N) {
    float dn = dinv[n];
    ew[rowstart[n] + cnt[n]] = make_float2(__int_as_float(n), dn * dn);
  }
}

// W [K][N] fp32 -> transposed split Wh/Wl [N][K] bf16 (k-contiguous)
__global__ void wsplit_kernel(const float* __restrict__ W, unsigned short* __restrict__ Wh,
                              unsigned short* __restrict__ Wl, int K, int N) {
  int i = blockIdx.x * blockDim.x + threadIdx.x;
  if (i < K * N) {
    int k = i / N, n = i % N;
    unsigned short h, l;
    split1(W[i], h, l);
    Wh[(size_t)n * K + k] = h;
    Wl[(size_t)n * K + k] = l;
  }
}

// ---------------- split-bf16 MFMA GEMM, 8-wave low-pressure blocks ----------------
// C[M x N] = A[M x K] @ B[K x N], BN == N. 512 threads = 8 waves (2 x 4):
// per-wave output 64 x (BN/4) -> acc 32 VGPR (BN=128), B-frags 16, A-frags 8.
// A fp32 split in-kernel -> LDS; B pre-split Wh/Wl [N][K] bf16 -> LDS (16B copies).
// Staging registers are transient (consumed before the MFMA section).
// acc = Ah*Bh + Ah*Bl + Al*Bh. Epilogue: per-wave LDS patch -> full-line float4 stores.

template <int BM, int BN>
__global__ void __launch_bounds__(512, 2)
gemm_mfma_kernel(const float* __restrict__ A, const unsigned short* __restrict__ Wh,
                 const unsigned short* __restrict__ Wl, float* __restrict__ C,
                 int M, int K) {
  constexpr int BK   = 32;
  constexpr int LDK  = 40;                 // bf16 elems per LDS row (80B)
  constexpr int MR   = BM / 2 / 16;        // 4
  constexpr int NR   = BN / 4 / 16;        // 2 (BN=128) or 1 (BN=64)
  constexpr int N    = BN;
  constexpr int LDC  = NR * 16 + 4;        // epilogue patch row stride (floats)
  constexpr int SMA  = (BM + BN) * LDK * 4;
  constexpr int SME  = 8 * 16 * LDC * 4;
  constexpr int SMEM = SMA > SME ? SMA : SME;

  __shared__ __align__(16) char smem[SMEM];
  unsigned short* Ah = (unsigned short*)smem;
  unsigned short* Al = Ah + (size_t)BM * LDK;
  unsigned short* Bh = Al + (size_t)BM * LDK;
  unsigned short* Bl = Bh + (size_t)BN * LDK;

  const int tid  = threadIdx.x;
  const int lane = tid & 63;
  const int w    = tid >> 6;          // 0..7
  const int wm   = w >> 2;            // 0..1 (64 rows each)
  const int wn   = w & 3;             // 0..3 (BN/4 cols each)
  const int fr   = lane & 15;
  const int fq   = lane >> 4;
  const int m0   = blockIdx.x * BM;

  const int a_c = tid & 7;            // k-chunk (4 floats)
  const int a_m = tid >> 3;           // row 0..63 (rows a_m, a_m+64)
  const int br  = tid >> 2;           // B row 0..127
  const int bj  = tid & 3;            // B 16B chunk

  f32x4 acc[MR][NR] = {};

  for (int kt = 0; kt < K; kt += BK) {
    // ---- global loads (transient regs, consumed below) ----
    float4 av[2];
#pragma unroll
    for (int p = 0; p < 2; ++p) {
      const int gm = m0 + a_m + 64 * p;
      av[p] = (gm < M) ? *(const float4*)&A[(size_t)gm * K + kt + 4 * a_c]
                       : make_float4(0.f, 0.f, 0.f, 0.f);
    }
    uint4 bht, blt;
    if (tid < BN * 4) {
      bht = *(const uint4*)&Wh[(size_t)br * K + kt + 8 * bj];
      blt = *(const uint4*)&Wl[(size_t)br * K + kt + 8 * bj];
    }

    __syncthreads();   // previous tile's LDS frag reads complete

    // ---- A split + store; B copy ----
#pragma unroll
    for (int p = 0; p < 2; ++p) {
      const int r = a_m + 64 * p;
      ushort4v hv, lv;
      split1(av[p].x, ((unsigned short*)&hv)[0], ((unsigned short*)&lv)[0]);
      split1(av[p].y, ((unsigned short*)&hv)[1], ((unsigned short*)&lv)[1]);
      split1(av[p].z, ((unsigned short*)&hv)[2], ((unsigned short*)&lv)[2]);
      split1(av[p].w, ((unsigned short*)&hv)[3], ((unsigned short*)&lv)[3]);
      *(ushort4v*)((char*)Ah + r * (LDK * 2) + a_c * 8) = hv;
      *(ushort4v*)((char*)Al + r * (LDK * 2) + a_c * 8) = lv;
    }
    if (tid < BN * 4) {
      *(uint4*)((char*)Bh + br * (LDK * 2) + 16 * bj) = bht;
      *(uint4*)((char*)Bl + br * (LDK * 2) + 16 * bj) = blt;
    }
    __syncthreads();

    // ---- fragments + MFMA ----
    bf16x8 bh[NR], bl[NR];
#pragma unroll
    for (int ni = 0; ni < NR; ++ni) {
      const int r = wn * (NR * 16) + ni * 16 + fr;
      bh[ni] = *(const bf16x8*)((const char*)Bh + r * (LDK * 2) + fq * 16);
      bl[ni] = *(const bf16x8*)((const char*)Bl + r * (LDK * 2) + fq * 16);
    }
#pragma unroll
    for (int mi = 0; mi < MR; ++mi) {
      const int r = wm * 64 + mi * 16 + fr;
      bf16x8 ah = *(const bf16x8*)((const char*)Ah + r * (LDK * 2) + fq * 16);
      bf16x8 al = *(const bf16x8*)((const char*)Al + r * (LDK * 2) + fq * 16);
#pragma unroll
      for (int ni = 0; ni < NR; ++ni) {
        acc[mi][ni] = __builtin_amdgcn_mfma_f32_16x16x32_bf16(ah, bh[ni], acc[mi][ni], 0, 0, 0);
        acc[mi][ni] = __builtin_amdgcn_mfma_f32_16x16x32_bf16(ah, bl[ni], acc[mi][ni], 0, 0, 0);
        acc[mi][ni] = __builtin_amdgcn_mfma_f32_16x16x32_bf16(al, bh[ni], acc[mi][ni], 0, 0, 0);
      }
    }
  }

  // ---- epilogue: per-wave LDS patch -> full-line float4 stores ----
  // Wave's C slice per mi: 16 rows x NR*16 cols at col wn*NR*16. For BN=128 the
  // 32-col slice is exactly one aligned 128B line per row.
  __syncthreads();   // all frag reads done; smem reused
  {
    float* cst = (float*)smem + (size_t)w * (16 * LDC);
    constexpr int CPR   = NR * 4;        // float4 chunks per patch row
    constexpr int EPASS = 16 * CPR / 64 > 0 ? (16 * CPR + 63) / 64 : 1;
#pragma unroll
    for (int mi = 0; mi < MR; ++mi) {
#pragma unroll
      for (int ni = 0; ni < NR; ++ni)
#pragma unroll
        for (int r = 0; r < 4; ++r)
          cst[(fq * 4 + r) * LDC + ni * 16 + fr] = acc[mi][ni][r];
#pragma unroll
      for (int p = 0; p < EPASS; ++p) {
        const int idx = p * 64 + lane;
        if (idx < 16 * CPR) {
          const int row = idx / CPR;
          const int ch  = idx % CPR;
          const int gm  = m0 + wm * 64 + mi * 16 + row;
          float4 v = *(const float4*)&cst[row * LDC + ch * 4];
          if (gm < M) *(float4*)&C[(size_t)gm * N + wn * (NR * 16) + ch * 4] = v;
        }
      }
    }
  }
}

// ---------------- CSR pull aggregation: float4/lane, multi-edge per wave ----------------

template <int F>
__global__ void agg_kernel(const float* __restrict__ hin, const int* __restrict__ rowstart,
                           const int* __restrict__ cnt, const float2* __restrict__ ew,
                           const float* __restrict__ bias, float* __restrict__ outp, int N) {
  constexpr int LPE = F / 4;    // lanes per edge (float4 each)
  constexpr int EPW = 64 / LPE; // edge slots per wave
  const int wave = (int)((blockIdx.x * (size_t)blockDim.x + threadIdx.x) >> 6);
  if (wave >= N) return;
  const int lane = threadIdx.x & 63;
  const int sub  = lane / LPE;
  const int c    = lane % LPE;
  const int n    = wave;

  const int beg = rowstart[n];
  const int end = beg + cnt[n] + 1;   // incl. self edge

  float ax = 0.f, ay = 0.f, az = 0.f, aw = 0.f;
  int j = beg + sub;
  for (; j + EPW < end; j += 2 * EPW) {
    const float2 e0 = ew[j];
    const float2 e1 = ew[j + EPW];
    const float4 v0 = *(const float4*)&hin[(size_t)__float_as_int(e0.x) * F + c * 4];
    const float4 v1 = *(const float4*)&hin[(size_t)__float_as_int(e1.x) * F + c * 4];
    ax = fmaf(v0.x, e0.y, ax); ay = fmaf(v0.y, e0.y, ay);
    az = fmaf(v0.z, e0.y, az); aw = fmaf(v0.w, e0.y, aw);
    ax = fmaf(v1.x, e1.y, ax); ay = fmaf(v1.y, e1.y, ay);
    az = fmaf(v1.z, e1.y, az); aw = fmaf(v1.w, e1.y, aw);
  }
  if (j < end) {
    const float2 e = ew[j];
    const float4 v = *(const float4*)&hin[(size_t)__float_as_int(e.x) * F + c * 4];
    ax = fmaf(v.x, e.y, ax); ay = fmaf(v.y, e.y, ay);
    az = fmaf(v.z, e.y, az); aw = fmaf(v.w, e.y, aw);
  }

#pragma unroll
  for (int d = LPE; d < 64; d <<= 1) {
    ax += __shfl_xor(ax, d);
    ay += __shfl_xor(ay, d);
    az += __shfl_xor(az, d);
    aw += __shfl_xor(aw, d);
  }

  if (lane < LPE) {
    const float4 bb = *(const float4*)&bias[c * 4];
    float4 r;
    r.x = fmaxf(ax + bb.x, 0.f);
    r.y = fmaxf(ay + bb.y, 0.f);
    r.z = fmaxf(az + bb.z, 0.f);
    r.w = fmaxf(aw + bb.w, 0.f);
    *(float4*)&outp[(size_t)n * F + c * 4] = r;
  }
}

// ---------------- launch ----------------

extern "C" void kernel_launch(void* const* d_in, const int* in_sizes, int n_in,
                              void* d_out, int out_size, void* d_ws, size_t ws_size,
                              hipStream_t stream) {
  const float* x  = (const float*)d_in[0];
  const int*   ei = (const int*)d_in[1];
  const float* W1 = (const float*)d_in[2];
  const float* b1 = (const float*)d_in[3];
  const float* W2 = (const float*)d_in[4];
  const float* b2 = (const float*)d_in[5];
  float* out = (float*)d_out;

  const int F1 = in_sizes[3];           // 128
  const int F2 = in_sizes[5];           // 64
  const int F0 = in_sizes[2] / F1;      // 512
  const int N  = in_sizes[0] / F0;      // 100000
  const int E  = in_sizes[1] / 2;       // 1600000

  char* ws = (char*)d_ws;
  size_t off = 0;
  auto alloc = [&](size_t bytes) -> void* {
    void* p = ws + off;
    off = (off + bytes + 255) & ~(size_t)255;
    return p;
  };

  int*    cnt      = (int*)alloc((size_t)N * 4);
  int*    fillc    = (int*)alloc((size_t)N * 4);
  int*    rowstart = (int*)alloc((size_t)N * 4);
  float*  dinv     = (float*)alloc((size_t)N * 4);
  const int nb     = (N + SCAN_B - 1) / SCAN_B;
  int*    bsum     = (int*)alloc((size_t)nb * 4);
  float2* ew       = (float2*)alloc(((size_t)E + N) * 8);
  float*  h        = (float*)alloc((size_t)N * F1 * 4);
  float*  h1       = (float*)alloc((size_t)N * F1 * 4);
  float*  h2       = h;  // reuse
  unsigned short* W1h = (unsigned short*)alloc((size_t)F0 * F1 * 2);
  unsigned short* W1l = (unsigned short*)alloc((size_t)F0 * F1 * 2);
  unsigned short* W2h = (unsigned short*)alloc((size_t)F1 * F2 * 2);
  unsigned short* W2l = (unsigned short*)alloc((size_t)F1 * F2 * 2);

  zero2_kernel<<<(N + 255) / 256, 256, 0, stream>>>(cnt, fillc, N);
  count_kernel<<<(E + 255) / 256, 256, 0, stream>>>(ei, cnt, E);
  dinv_kernel<<<(N + 255) / 256, 256, 0, stream>>>(cnt, dinv, N);
  scan1_kernel<<<nb, SCAN_B, 0, stream>>>(cnt, rowstart, bsum, N);
  scan2_kernel<<<1, SCAN_B, 0, stream>>>(bsum, nb);
  scan3_kernel<<<(N + 255) / 256, 256, 0, stream>>>(rowstart, bsum, N);
  fill_kernel<<<(E + 255) / 256, 256, 0, stream>>>(ei, fillc, rowstart, dinv, ew, E);
  selfedge_kernel<<<(N + 255) / 256, 256, 0, stream>>>(rowstart, cnt, dinv, ew, N);
  wsplit_kernel<<<(F0 * F1 + 255) / 256, 256, 0, stream>>>(W1, W1h, W1l, F0, F1);
  wsplit_kernel<<<(F1 * F2 + 255) / 256, 256, 0, stream>>>(W2, W2h, W2l, F1, F2);

  // layer 1: h = x@W1 ; h1 = relu(agg(h) + b1)
  gemm_mfma_kernel<128, 128><<<(N + 127) / 128, 512, 0, stream>>>(x, W1h, W1l, h, N, F0);
  {
    const long blocks = ((long)N * 64 + 255) / 256;
    agg_kernel<128><<<(int)blocks, 256, 0, stream>>>(h, rowstart, cnt, ew, b1, h1, N);
  }

  // layer 2: h2 = h1@W2 ; out = relu(agg(h2) + b2)
  gemm_mfma_kernel<128, 64><<<(N + 127) / 128, 512, 0, stream>>>(h1, W2h, W2l, h2, N, F1);
  {
    const long blocks = ((long)N * 64 + 255) / 256;
    agg_kernel<64><<<(int)blocks, 256, 0, stream>>>(h2, rowstart, cnt, ew, b2, out, N);
  }
}

// Round 8
// 378.405 us; speedup vs baseline: 1.5025x; 1.1958x over previous
//
#include <hip/hip_runtime.h>

#define SCAN_B 1024

using bf16x8 = __attribute__((ext_vector_type(8))) short;
using f32x4  = __attribute__((ext_vector_type(4))) float;
typedef unsigned short ushort4v __attribute__((ext_vector_type(4)));
typedef _Float16 half4v __attribute__((ext_vector_type(4)));
typedef _Float16 half8v __attribute__((ext_vector_type(8)));

// split fp32 into bf16 hi (truncation) + bf16 lo (RNE of exact remainder)
__device__ inline void split1(float x, unsigned short& h, unsigned short& l) {
  unsigned u  = __float_as_uint(x);
  unsigned hu = u & 0xFFFF0000u;
  float lo = x - __uint_as_float(hu);
  unsigned lu = __float_as_uint(lo);
  h = (unsigned short)(hu >> 16);
  l = (unsigned short)((lu + 0x7FFFu + ((lu >> 16) & 1u)) >> 16);
}

// ---------------- precompute kernels ----------------

__global__ void zero2_kernel(int* __restrict__ a, int* __restrict__ b, int n) {
  int i = blockIdx.x * blockDim.x + threadIdx.x;
  if (i < n) { a[i] = 0; b[i] = 0; }
}

__global__ void count_kernel(const int* __restrict__ ei, int* __restrict__ cnt, int E) {
  int i = blockIdx.x * blockDim.x + threadIdx.x;
  if (i < E) atomicAdd(&cnt[ei[E + i]], 1);
}

__global__ void dinv_kernel(const int* __restrict__ cnt, float* __restrict__ dinv, int n) {
  int i = blockIdx.x * blockDim.x + threadIdx.x;
  if (i < n) dinv[i] = rsqrtf((float)(cnt[i] + 1));
}

// scan over (cnt[i] + 1): row length includes the appended self edge
__global__ void scan1_kernel(const int* __restrict__ cnt, int* __restrict__ rowstart,
                             int* __restrict__ bsum, int n) {
  __shared__ int sm[SCAN_B];
  const int t = threadIdx.x;
  const int i = blockIdx.x * SCAN_B + t;
  int v = (i < n) ? (cnt[i] + 1) : 0;
  sm[t] = v;
  __syncthreads();
  for (int off = 1; off < SCAN_B; off <<= 1) {
    int x = (t >= off) ? sm[t - off] : 0;
    __syncthreads();
    if (t >= off) sm[t] += x;
    __syncthreads();
  }
  if (i < n) rowstart[i] = sm[t] - v;
  if (t == SCAN_B - 1) bsum[blockIdx.x] = sm[t];
}

__global__ void scan2_kernel(int* __restrict__ bsum, int nb) {
  __shared__ int sm[SCAN_B];
  const int t = threadIdx.x;
  int v = (t < nb) ? bsum[t] : 0;
  sm[t] = v;
  __syncthreads();
  for (int off = 1; off < SCAN_B; off <<= 1) {
    int x = (t >= off) ? sm[t - off] : 0;
    __syncthreads();
    if (t >= off) sm[t] += x;
    __syncthreads();
  }
  if (t < nb) bsum[t] = sm[t] - v;
}

__global__ void scan3_kernel(int* __restrict__ rowstart, const int* __restrict__ bsum, int n) {
  int i = blockIdx.x * blockDim.x + threadIdx.x;
  if (i < n) rowstart[i] += bsum[i / SCAN_B];
}

__global__ void fill_kernel(const int* __restrict__ ei, int* __restrict__ fillc,
                            const int* __restrict__ rowstart, const float* __restrict__ dinv,
                            float2* __restrict__ ew, int E) {
  int e = blockIdx.x * blockDim.x + threadIdx.x;
  if (e < E) {
    int s = ei[e];
    int d = ei[E + e];
    int p = atomicAdd(&fillc[d], 1);
    ew[rowstart[d] + p] = make_float2(__int_as_float(s), dinv[s] * dinv[d]);
  }
}

// self edge goes in the last slot of each row: weight dinv^2
__global__ void selfedge_kernel(const int* __restrict__ rowstart, const int* __restrict__ cnt,
                                const float* __restrict__ dinv, float2* __restrict__ ew, int N) {
  int n = blockIdx.x * blockDim.x + threadIdx.x;
  if (n < N) {
    float dn = dinv[n];
    ew[rowstart[n] + cnt[n]] = make_float2(__int_as_float(n), dn * dn);
  }
}

// W [K][N] fp32 -> transposed split Wh/Wl [N][K] bf16 (k-contiguous)
__global__ void wsplit_kernel(const float* __restrict__ W, unsigned short* __restrict__ Wh,
                              unsigned short* __restrict__ Wl, int K, int N) {
  int i = blockIdx.x * blockDim.x + threadIdx.x;
  if (i < K * N) {
    int k = i / N, n = i % N;
    unsigned short h, l;
    split1(W[i], h, l);
    Wh[(size_t)n * K + k] = h;
    Wl[(size_t)n * K + k] = l;
  }
}

// ---------------- split-bf16 MFMA GEMM, 8-wave low-pressure blocks ----------------
// C[M x N] = A[M x K] @ B[K x N], BN == N. 512 threads = 8 waves (2 x 4).
// A fp32 split in-kernel -> LDS; B pre-split Wh/Wl [N][K] bf16 -> LDS.
// acc = Ah*Bh + Ah*Bl + Al*Bh. Output type CT = float or _Float16.
// Epilogue: per-wave LDS patch -> full-line coalesced stores.

template <int BM, int BN, typename CT>
__global__ void __launch_bounds__(512, 2)
gemm_mfma_kernel(const float* __restrict__ A, const unsigned short* __restrict__ Wh,
                 const unsigned short* __restrict__ Wl, CT* __restrict__ C,
                 int M, int K) {
  constexpr int BK   = 32;
  constexpr int LDK  = 40;                 // bf16 elems per LDS row (80B)
  constexpr int MR   = BM / 2 / 16;        // 4
  constexpr int NR   = BN / 4 / 16;        // 2 (BN=128) or 1 (BN=64)
  constexpr int N    = BN;
  constexpr int LDC  = NR * 16 + 4;        // epilogue patch row stride (floats)
  constexpr int SMA  = (BM + BN) * LDK * 4;
  constexpr int SME  = 8 * 16 * LDC * 4;
  constexpr int SMEM = SMA > SME ? SMA : SME;

  __shared__ __align__(16) char smem[SMEM];
  unsigned short* Ah = (unsigned short*)smem;
  unsigned short* Al = Ah + (size_t)BM * LDK;
  unsigned short* Bh = Al + (size_t)BM * LDK;
  unsigned short* Bl = Bh + (size_t)BN * LDK;

  const int tid  = threadIdx.x;
  const int lane = tid & 63;
  const int w    = tid >> 6;          // 0..7
  const int wm   = w >> 2;            // 0..1 (64 rows each)
  const int wn   = w & 3;             // 0..3
  const int fr   = lane & 15;
  const int fq   = lane >> 4;
  const int m0   = blockIdx.x * BM;

  const int a_c = tid & 7;            // k-chunk (4 floats)
  const int a_m = tid >> 3;           // row 0..63
  const int br  = tid >> 2;           // B row 0..127
  const int bj  = tid & 3;            // B 16B chunk

  f32x4 acc[MR][NR] = {};

  for (int kt = 0; kt < K; kt += BK) {
    // ---- global loads (transient regs) ----
    float4 av[2];
#pragma unroll
    for (int p = 0; p < 2; ++p) {
      const int gm = m0 + a_m + 64 * p;
      av[p] = (gm < M) ? *(const float4*)&A[(size_t)gm * K + kt + 4 * a_c]
                       : make_float4(0.f, 0.f, 0.f, 0.f);
    }
    uint4 bht, blt;
    if (tid < BN * 4) {
      bht = *(const uint4*)&Wh[(size_t)br * K + kt + 8 * bj];
      blt = *(const uint4*)&Wl[(size_t)br * K + kt + 8 * bj];
    }

    __syncthreads();   // previous tile's LDS frag reads complete

    // ---- A split + store; B copy ----
#pragma unroll
    for (int p = 0; p < 2; ++p) {
      const int r = a_m + 64 * p;
      ushort4v hv, lv;
      split1(av[p].x, ((unsigned short*)&hv)[0], ((unsigned short*)&lv)[0]);
      split1(av[p].y, ((unsigned short*)&hv)[1], ((unsigned short*)&lv)[1]);
      split1(av[p].z, ((unsigned short*)&hv)[2], ((unsigned short*)&lv)[2]);
      split1(av[p].w, ((unsigned short*)&hv)[3], ((unsigned short*)&lv)[3]);
      *(ushort4v*)((char*)Ah + r * (LDK * 2) + a_c * 8) = hv;
      *(ushort4v*)((char*)Al + r * (LDK * 2) + a_c * 8) = lv;
    }
    if (tid < BN * 4) {
      *(uint4*)((char*)Bh + br * (LDK * 2) + 16 * bj) = bht;
      *(uint4*)((char*)Bl + br * (LDK * 2) + 16 * bj) = blt;
    }
    __syncthreads();

    // ---- fragments + MFMA ----
    bf16x8 bh[NR], bl[NR];
#pragma unroll
    for (int ni = 0; ni < NR; ++ni) {
      const int r = wn * (NR * 16) + ni * 16 + fr;
      bh[ni] = *(const bf16x8*)((const char*)Bh + r * (LDK * 2) + fq * 16);
      bl[ni] = *(const bf16x8*)((const char*)Bl + r * (LDK * 2) + fq * 16);
    }
#pragma unroll
    for (int mi = 0; mi < MR; ++mi) {
      const int r = wm * 64 + mi * 16 + fr;
      bf16x8 ah = *(const bf16x8*)((const char*)Ah + r * (LDK * 2) + fq * 16);
      bf16x8 al = *(const bf16x8*)((const char*)Al + r * (LDK * 2) + fq * 16);
#pragma unroll
      for (int ni = 0; ni < NR; ++ni) {
        acc[mi][ni] = __builtin_amdgcn_mfma_f32_16x16x32_bf16(ah, bh[ni], acc[mi][ni], 0, 0, 0);
        acc[mi][ni] = __builtin_amdgcn_mfma_f32_16x16x32_bf16(ah, bl[ni], acc[mi][ni], 0, 0, 0);
        acc[mi][ni] = __builtin_amdgcn_mfma_f32_16x16x32_bf16(al, bh[ni], acc[mi][ni], 0, 0, 0);
      }
    }
  }

  // ---- epilogue: per-wave LDS patch -> coalesced stores ----
  __syncthreads();   // all frag reads done; smem reused
  {
    float* cst = (float*)smem + (size_t)w * (16 * LDC);
    constexpr int CPR   = NR * 4;        // float4 chunks per patch row
    constexpr int EPASS = (16 * CPR + 63) / 64;
#pragma unroll
    for (int mi = 0; mi < MR; ++mi) {
#pragma unroll
      for (int ni = 0; ni < NR; ++ni)
#pragma unroll
        for (int r = 0; r < 4; ++r)
          cst[(fq * 4 + r) * LDC + ni * 16 + fr] = acc[mi][ni][r];
#pragma unroll
      for (int p = 0; p < EPASS; ++p) {
        const int idx = p * 64 + lane;
        if (idx < 16 * CPR) {
          const int row = idx / CPR;
          const int ch  = idx % CPR;
          const int gm  = m0 + wm * 64 + mi * 16 + row;
          float4 v = *(const float4*)&cst[row * LDC + ch * 4];
          if (gm < M) {
            if constexpr (sizeof(CT) == 2) {
              half4v hv = {(_Float16)v.x, (_Float16)v.y, (_Float16)v.z, (_Float16)v.w};
              *(half4v*)&C[(size_t)gm * N + wn * (NR * 16) + ch * 4] = hv;
            } else {
              *(float4*)&C[(size_t)gm * N + wn * (NR * 16) + ch * 4] = v;
            }
          }
        }
      }
    }
  }
}

// ---------------- CSR pull aggregation over fp16 rows ----------------
// Lane loads 8 halfs (16B). F=128: 16 lanes/edge, 4 slots/wave; F=64: 8 lanes/edge, 8 slots.
// Unroll x4 -> up to 16 edges in flight per wave. fp32 accumulate, fp32 output.

template <int F>
__global__ void agg_kernel(const _Float16* __restrict__ hin, const int* __restrict__ rowstart,
                           const int* __restrict__ cnt, const float2* __restrict__ ew,
                           const float* __restrict__ bias, float* __restrict__ outp, int N) {
  constexpr int LPE = F / 8;    // lanes per edge
  constexpr int EPW = 64 / LPE; // edge slots per wave
  const int wave = (int)((blockIdx.x * (size_t)blockDim.x + threadIdx.x) >> 6);
  if (wave >= N) return;
  const int lane = threadIdx.x & 63;
  const int sub  = lane / LPE;
  const int c    = lane % LPE;
  const int n    = wave;

  const int beg = rowstart[n];
  const int end = beg + cnt[n] + 1;   // incl. self edge

  float acc[8] = {};
  int j = beg + sub;
  for (; j + 3 * EPW < end; j += 4 * EPW) {
    const float2 e0 = ew[j];
    const float2 e1 = ew[j + EPW];
    const float2 e2 = ew[j + 2 * EPW];
    const float2 e3 = ew[j + 3 * EPW];
    const half8v v0 = *(const half8v*)&hin[(size_t)__float_as_int(e0.x) * F + c * 8];
    const half8v v1 = *(const half8v*)&hin[(size_t)__float_as_int(e1.x) * F + c * 8];
    const half8v v2 = *(const half8v*)&hin[(size_t)__float_as_int(e2.x) * F + c * 8];
    const half8v v3 = *(const half8v*)&hin[(size_t)__float_as_int(e3.x) * F + c * 8];
#pragma unroll
    for (int i = 0; i < 8; ++i) {
      acc[i] = fmaf((float)v0[i], e0.y, acc[i]);
      acc[i] = fmaf((float)v1[i], e1.y, acc[i]);
      acc[i] = fmaf((float)v2[i], e2.y, acc[i]);
      acc[i] = fmaf((float)v3[i], e3.y, acc[i]);
    }
  }
  for (; j < end; j += EPW) {
    const float2 e = ew[j];
    const half8v v = *(const half8v*)&hin[(size_t)__float_as_int(e.x) * F + c * 8];
#pragma unroll
    for (int i = 0; i < 8; ++i) acc[i] = fmaf((float)v[i], e.y, acc[i]);
  }

  // reduce across edge slots
#pragma unroll
  for (int d = LPE; d < 64; d <<= 1)
#pragma unroll
    for (int i = 0; i < 8; ++i) acc[i] += __shfl_xor(acc[i], d);

  if (lane < LPE) {
    const float4 b0 = *(const float4*)&bias[c * 8];
    const float4 b1 = *(const float4*)&bias[c * 8 + 4];
    float4 r0, r1;
    r0.x = fmaxf(acc[0] + b0.x, 0.f);
    r0.y = fmaxf(acc[1] + b0.y, 0.f);
    r0.z = fmaxf(acc[2] + b0.z, 0.f);
    r0.w = fmaxf(acc[3] + b0.w, 0.f);
    r1.x = fmaxf(acc[4] + b1.x, 0.f);
    r1.y = fmaxf(acc[5] + b1.y, 0.f);
    r1.z = fmaxf(acc[6] + b1.z, 0.f);
    r1.w = fmaxf(acc[7] + b1.w, 0.f);
    *(float4*)&outp[(size_t)n * F + c * 8] = r0;
    *(float4*)&outp[(size_t)n * F + c * 8 + 4] = r1;
  }
}

// ---------------- launch ----------------

extern "C" void kernel_launch(void* const* d_in, const int* in_sizes, int n_in,
                              void* d_out, int out_size, void* d_ws, size_t ws_size,
                              hipStream_t stream) {
  const float* x  = (const float*)d_in[0];
  const int*   ei = (const int*)d_in[1];
  const float* W1 = (const float*)d_in[2];
  const float* b1 = (const float*)d_in[3];
  const float* W2 = (const float*)d_in[4];
  const float* b2 = (const float*)d_in[5];
  float* out = (float*)d_out;

  const int F1 = in_sizes[3];           // 128
  const int F2 = in_sizes[5];           // 64
  const int F0 = in_sizes[2] / F1;      // 512
  const int N  = in_sizes[0] / F0;      // 100000
  const int E  = in_sizes[1] / 2;       // 1600000

  char* ws = (char*)d_ws;
  size_t off = 0;
  auto alloc = [&](size_t bytes) -> void* {
    void* p = ws + off;
    off = (off + bytes + 255) & ~(size_t)255;
    return p;
  };

  int*    cnt      = (int*)alloc((size_t)N * 4);
  int*    fillc    = (int*)alloc((size_t)N * 4);
  int*    rowstart = (int*)alloc((size_t)N * 4);
  float*  dinv     = (float*)alloc((size_t)N * 4);
  const int nb     = (N + SCAN_B - 1) / SCAN_B;
  int*    bsum     = (int*)alloc((size_t)nb * 4);
  float2* ew       = (float2*)alloc(((size_t)E + N) * 8);
  _Float16* h      = (_Float16*)alloc((size_t)N * F1 * 2);  // fp16 GEMM1 out
  float*  h1       = (float*)alloc((size_t)N * F1 * 4);     // fp32 agg1 out
  _Float16* h2     = h;  // fp16 GEMM2 out, reuses h (dead after agg1)
  unsigned short* W1h = (unsigned short*)alloc((size_t)F0 * F1 * 2);
  unsigned short* W1l = (unsigned short*)alloc((size_t)F0 * F1 * 2);
  unsigned short* W2h = (unsigned short*)alloc((size_t)F1 * F2 * 2);
  unsigned short* W2l = (unsigned short*)alloc((size_t)F1 * F2 * 2);

  zero2_kernel<<<(N + 255) / 256, 256, 0, stream>>>(cnt, fillc, N);
  count_kernel<<<(E + 255) / 256, 256, 0, stream>>>(ei, cnt, E);
  dinv_kernel<<<(N + 255) / 256, 256, 0, stream>>>(cnt, dinv, N);
  scan1_kernel<<<nb, SCAN_B, 0, stream>>>(cnt, rowstart, bsum, N);
  scan2_kernel<<<1, SCAN_B, 0, stream>>>(bsum, nb);
  scan3_kernel<<<(N + 255) / 256, 256, 0, stream>>>(rowstart, bsum, N);
  fill_kernel<<<(E + 255) / 256, 256, 0, stream>>>(ei, fillc, rowstart, dinv, ew, E);
  selfedge_kernel<<<(N + 255) / 256, 256, 0, stream>>>(rowstart, cnt, dinv, ew, N);
  wsplit_kernel<<<(F0 * F1 + 255) / 256, 256, 0, stream>>>(W1, W1h, W1l, F0, F1);
  wsplit_kernel<<<(F1 * F2 + 255) / 256, 256, 0, stream>>>(W2, W2h, W2l, F1, F2);

  // layer 1: h = fp16(x@W1) ; h1 = relu(agg(h) + b1)  (fp32)
  gemm_mfma_kernel<128, 128, _Float16><<<(N + 127) / 128, 512, 0, stream>>>(x, W1h, W1l, h, N, F0);
  {
    const long blocks = ((long)N * 64 + 255) / 256;
    agg_kernel<128><<<(int)blocks, 256, 0, stream>>>(h, rowstart, cnt, ew, b1, h1, N);
  }

  // layer 2: h2 = fp16(h1@W2) ; out = relu(agg(h2) + b2)
  gemm_mfma_kernel<128, 64, _Float16><<<(N + 127) / 128, 512, 0, stream>>>(h1, W2h, W2l, h2, N, F1);
  {
    const long blocks = ((long)N * 64 + 255) / 256;
    agg_kernel<64><<<(int)blocks, 256, 0, stream>>>(h2, rowstart, cnt, ew, b2, out, N);
  }
}

// Round 9
// 374.764 us; speedup vs baseline: 1.5171x; 1.0097x over previous
//
#include <hip/hip_runtime.h>

#define SCAN_B 1024

using bf16x8 = __attribute__((ext_vector_type(8))) short;
using f32x4  = __attribute__((ext_vector_type(4))) float;
typedef unsigned short ushort4v __attribute__((ext_vector_type(4)));
typedef _Float16 half4v __attribute__((ext_vector_type(4)));
typedef _Float16 half8v __attribute__((ext_vector_type(8)));

// split fp32 into bf16 hi (truncation) + bf16 lo (RNE of exact remainder)
__device__ inline void split1(float x, unsigned short& h, unsigned short& l) {
  unsigned u  = __float_as_uint(x);
  unsigned hu = u & 0xFFFF0000u;
  float lo = x - __uint_as_float(hu);
  unsigned lu = __float_as_uint(lo);
  h = (unsigned short)(hu >> 16);
  l = (unsigned short)((lu + 0x7FFFu + ((lu >> 16) & 1u)) >> 16);
}

// ---------------- precompute kernels ----------------

__global__ void zero2_kernel(int* __restrict__ a, int* __restrict__ b, int n) {
  int i = blockIdx.x * blockDim.x + threadIdx.x;
  if (i < n) { a[i] = 0; b[i] = 0; }
}

__global__ void count_kernel(const int* __restrict__ ei, int* __restrict__ cnt, int E) {
  int i = blockIdx.x * blockDim.x + threadIdx.x;
  if (i < E) atomicAdd(&cnt[ei[E + i]], 1);
}

// scan over (cnt[i] + 1) (row length incl. self edge); also emits dinv = rsqrt(deg)
__global__ void scan1_kernel(const int* __restrict__ cnt, int* __restrict__ rowstart,
                             int* __restrict__ bsum, float* __restrict__ dinv, int n) {
  __shared__ int sm[SCAN_B];
  const int t = threadIdx.x;
  const int i = blockIdx.x * SCAN_B + t;
  int c = (i < n) ? cnt[i] : 0;
  if (i < n) dinv[i] = rsqrtf((float)(c + 1));
  int v = (i < n) ? (c + 1) : 0;
  sm[t] = v;
  __syncthreads();
  for (int off = 1; off < SCAN_B; off <<= 1) {
    int x = (t >= off) ? sm[t - off] : 0;
    __syncthreads();
    if (t >= off) sm[t] += x;
    __syncthreads();
  }
  if (i < n) rowstart[i] = sm[t] - v;
  if (t == SCAN_B - 1) bsum[blockIdx.x] = sm[t];
}

__global__ void scan2_kernel(int* __restrict__ bsum, int nb) {
  __shared__ int sm[SCAN_B];
  const int t = threadIdx.x;
  int v = (t < nb) ? bsum[t] : 0;
  sm[t] = v;
  __syncthreads();
  for (int off = 1; off < SCAN_B; off <<= 1) {
    int x = (t >= off) ? sm[t - off] : 0;
    __syncthreads();
    if (t >= off) sm[t] += x;
    __syncthreads();
  }
  if (t < nb) bsum[t] = sm[t] - v;
}

__global__ void scan3_kernel(int* __restrict__ rowstart, const int* __restrict__ bsum, int n) {
  int i = blockIdx.x * blockDim.x + threadIdx.x;
  if (i < n) rowstart[i] += bsum[i / SCAN_B];
}

// fused: real edges (i < E) + self edges (i >= E, n = i - E, last slot of row n)
__global__ void fillself_kernel(const int* __restrict__ ei, int* __restrict__ fillc,
                                const int* __restrict__ rowstart, const int* __restrict__ cnt,
                                const float* __restrict__ dinv, float2* __restrict__ ew,
                                int E, int N) {
  int i = blockIdx.x * blockDim.x + threadIdx.x;
  if (i < E) {
    int s = ei[i];
    int d = ei[E + i];
    int p = atomicAdd(&fillc[d], 1);
    ew[rowstart[d] + p] = make_float2(__int_as_float(s), dinv[s] * dinv[d]);
  } else if (i < E + N) {
    int n = i - E;
    float dn = dinv[n];
    ew[rowstart[n] + cnt[n]] = make_float2(__int_as_float(n), dn * dn);
  }
}

// both weights in one launch: W [K][N] fp32 -> transposed split [N][K] bf16
__global__ void wsplit2_kernel(const float* __restrict__ W1, unsigned short* __restrict__ W1h,
                               unsigned short* __restrict__ W1l, int K1, int N1,
                               const float* __restrict__ W2, unsigned short* __restrict__ W2h,
                               unsigned short* __restrict__ W2l, int K2, int N2) {
  int i = blockIdx.x * blockDim.x + threadIdx.x;
  const int n1 = K1 * N1;
  if (i < n1) {
    int k = i / N1, n = i % N1;
    unsigned short h, l;
    split1(W1[i], h, l);
    W1h[(size_t)n * K1 + k] = h;
    W1l[(size_t)n * K1 + k] = l;
  } else if (i < n1 + K2 * N2) {
    int j = i - n1;
    int k = j / N2, n = j % N2;
    unsigned short h, l;
    split1(W2[j], h, l);
    W2h[(size_t)n * K2 + k] = h;
    W2l[(size_t)n * K2 + k] = l;
  }
}

// ---------------- split-bf16 MFMA GEMM, 8-wave, reg-prefetch ----------------
// C[M x N] = A[M x K] @ B[K x N], BN == N. 512 threads = 8 waves (2 x 4).
// A fp32 split in-kernel -> LDS; B pre-split Wh/Wl [N][K] bf16 -> LDS.
// Next tile's global loads are issued after staging and drain under the MFMAs.
// acc = Ah*Bh + Ah*Bl + Al*Bh. CT = float or _Float16 output.

template <int BM, int BN, typename CT>
__global__ void __launch_bounds__(512, 2)
gemm_mfma_kernel(const float* __restrict__ A, const unsigned short* __restrict__ Wh,
                 const unsigned short* __restrict__ Wl, CT* __restrict__ C,
                 int M, int K) {
  constexpr int BK   = 32;
  constexpr int LDK  = 40;                 // bf16 elems per LDS row (80B)
  constexpr int MR   = BM / 2 / 16;        // 4
  constexpr int NR   = BN / 4 / 16;        // 2 (BN=128) or 1 (BN=64)
  constexpr int N    = BN;
  constexpr int LDC  = NR * 16 + 4;        // epilogue patch row stride (floats)
  constexpr int SMA  = (BM + BN) * LDK * 4;
  constexpr int SME  = 8 * 16 * LDC * 4;
  constexpr int SMEM = SMA > SME ? SMA : SME;

  __shared__ __align__(16) char smem[SMEM];
  unsigned short* Ah = (unsigned short*)smem;
  unsigned short* Al = Ah + (size_t)BM * LDK;
  unsigned short* Bh = Al + (size_t)BM * LDK;
  unsigned short* Bl = Bh + (size_t)BN * LDK;

  const int tid  = threadIdx.x;
  const int lane = tid & 63;
  const int w    = tid >> 6;          // 0..7
  const int wm   = w >> 2;            // 0..1 (64 rows each)
  const int wn   = w & 3;             // 0..3
  const int fr   = lane & 15;
  const int fq   = lane >> 4;
  const int m0   = blockIdx.x * BM;

  const int a_c = tid & 7;            // k-chunk (4 floats)
  const int a_m = tid >> 3;           // row 0..63
  const int br  = tid >> 2;           // B row 0..127
  const int bj  = tid & 3;            // B 16B chunk

  float4 av[2];
  uint4  bht, blt;

  auto loadA = [&](int kt) {
#pragma unroll
    for (int p = 0; p < 2; ++p) {
      const int gm = m0 + a_m + 64 * p;
      av[p] = (gm < M) ? *(const float4*)&A[(size_t)gm * K + kt + 4 * a_c]
                       : make_float4(0.f, 0.f, 0.f, 0.f);
    }
  };
  auto loadB = [&](int kt) {
    if (tid < BN * 4) {
      bht = *(const uint4*)&Wh[(size_t)br * K + kt + 8 * bj];
      blt = *(const uint4*)&Wl[(size_t)br * K + kt + 8 * bj];
    }
  };

  f32x4 acc[MR][NR] = {};

  loadA(0);
  loadB(0);

  for (int kt = 0; kt < K; kt += BK) {
    __syncthreads();   // previous tile's LDS frag reads complete

    // ---- A split + store; B copy (consumes staged regs) ----
#pragma unroll
    for (int p = 0; p < 2; ++p) {
      const int r = a_m + 64 * p;
      ushort4v hv, lv;
      split1(av[p].x, ((unsigned short*)&hv)[0], ((unsigned short*)&lv)[0]);
      split1(av[p].y, ((unsigned short*)&hv)[1], ((unsigned short*)&lv)[1]);
      split1(av[p].z, ((unsigned short*)&hv)[2], ((unsigned short*)&lv)[2]);
      split1(av[p].w, ((unsigned short*)&hv)[3], ((unsigned short*)&lv)[3]);
      *(ushort4v*)((char*)Ah + r * (LDK * 2) + a_c * 8) = hv;
      *(ushort4v*)((char*)Al + r * (LDK * 2) + a_c * 8) = lv;
    }
    if (tid < BN * 4) {
      *(uint4*)((char*)Bh + br * (LDK * 2) + 16 * bj) = bht;
      *(uint4*)((char*)Bl + br * (LDK * 2) + 16 * bj) = blt;
    }
    __syncthreads();

    // ---- issue next tile's loads; they drain under the MFMA section ----
    if (kt + BK < K) {
      loadA(kt + BK);
      loadB(kt + BK);
    }

    // ---- fragments + MFMA ----
    bf16x8 bh[NR], bl[NR];
#pragma unroll
    for (int ni = 0; ni < NR; ++ni) {
      const int r = wn * (NR * 16) + ni * 16 + fr;
      bh[ni] = *(const bf16x8*)((const char*)Bh + r * (LDK * 2) + fq * 16);
      bl[ni] = *(const bf16x8*)((const char*)Bl + r * (LDK * 2) + fq * 16);
    }
#pragma unroll
    for (int mi = 0; mi < MR; ++mi) {
      const int r = wm * 64 + mi * 16 + fr;
      bf16x8 ah = *(const bf16x8*)((const char*)Ah + r * (LDK * 2) + fq * 16);
      bf16x8 al = *(const bf16x8*)((const char*)Al + r * (LDK * 2) + fq * 16);
#pragma unroll
      for (int ni = 0; ni < NR; ++ni) {
        acc[mi][ni] = __builtin_amdgcn_mfma_f32_16x16x32_bf16(ah, bh[ni], acc[mi][ni], 0, 0, 0);
        acc[mi][ni] = __builtin_amdgcn_mfma_f32_16x16x32_bf16(ah, bl[ni], acc[mi][ni], 0, 0, 0);
        acc[mi][ni] = __builtin_amdgcn_mfma_f32_16x16x32_bf16(al, bh[ni], acc[mi][ni], 0, 0, 0);
      }
    }
  }

  // ---- epilogue: per-wave LDS patch -> coalesced stores ----
  __syncthreads();   // all frag reads done; smem reused
  {
    float* cst = (float*)smem + (size_t)w * (16 * LDC);
    constexpr int CPR   = NR * 4;        // float4 chunks per patch row
    constexpr int EPASS = (16 * CPR + 63) / 64;
#pragma unroll
    for (int mi = 0; mi < MR; ++mi) {
#pragma unroll
      for (int ni = 0; ni < NR; ++ni)
#pragma unroll
        for (int r = 0; r < 4; ++r)
          cst[(fq * 4 + r) * LDC + ni * 16 + fr] = acc[mi][ni][r];
#pragma unroll
      for (int p = 0; p < EPASS; ++p) {
        const int idx = p * 64 + lane;
        if (idx < 16 * CPR) {
          const int row = idx / CPR;
          const int ch  = idx % CPR;
          const int gm  = m0 + wm * 64 + mi * 16 + row;
          float4 v = *(const float4*)&cst[row * LDC + ch * 4];
          if (gm < M) {
            if constexpr (sizeof(CT) == 2) {
              half4v hv = {(_Float16)v.x, (_Float16)v.y, (_Float16)v.z, (_Float16)v.w};
              *(half4v*)&C[(size_t)gm * N + wn * (NR * 16) + ch * 4] = hv;
            } else {
              *(float4*)&C[(size_t)gm * N + wn * (NR * 16) + ch * 4] = v;
            }
          }
        }
      }
    }
  }
}

// ---------------- CSR pull aggregation over fp16 rows ----------------
// Lane loads 8 halfs (16B). F=128: 16 lanes/edge, 4 slots/wave; F=64: 8 lanes/edge, 8 slots.
// Unroll x4 -> up to 16 edges in flight per wave. fp32 accumulate, fp32 output.

template <int F>
__global__ void agg_kernel(const _Float16* __restrict__ hin, const int* __restrict__ rowstart,
                           const int* __restrict__ cnt, const float2* __restrict__ ew,
                           const float* __restrict__ bias, float* __restrict__ outp, int N) {
  constexpr int LPE = F / 8;    // lanes per edge
  constexpr int EPW = 64 / LPE; // edge slots per wave
  const int wave = (int)((blockIdx.x * (size_t)blockDim.x + threadIdx.x) >> 6);
  if (wave >= N) return;
  const int lane = threadIdx.x & 63;
  const int sub  = lane / LPE;
  const int c    = lane % LPE;
  const int n    = wave;

  const int beg = rowstart[n];
  const int end = beg + cnt[n] + 1;   // incl. self edge

  float acc[8] = {};
  int j = beg + sub;
  for (; j + 3 * EPW < end; j += 4 * EPW) {
    const float2 e0 = ew[j];
    const float2 e1 = ew[j + EPW];
    const float2 e2 = ew[j + 2 * EPW];
    const float2 e3 = ew[j + 3 * EPW];
    const half8v v0 = *(const half8v*)&hin[(size_t)__float_as_int(e0.x) * F + c * 8];
    const half8v v1 = *(const half8v*)&hin[(size_t)__float_as_int(e1.x) * F + c * 8];
    const half8v v2 = *(const half8v*)&hin[(size_t)__float_as_int(e2.x) * F + c * 8];
    const half8v v3 = *(const half8v*)&hin[(size_t)__float_as_int(e3.x) * F + c * 8];
#pragma unroll
    for (int i = 0; i < 8; ++i) {
      acc[i] = fmaf((float)v0[i], e0.y, acc[i]);
      acc[i] = fmaf((float)v1[i], e1.y, acc[i]);
      acc[i] = fmaf((float)v2[i], e2.y, acc[i]);
      acc[i] = fmaf((float)v3[i], e3.y, acc[i]);
    }
  }
  for (; j < end; j += EPW) {
    const float2 e = ew[j];
    const half8v v = *(const half8v*)&hin[(size_t)__float_as_int(e.x) * F + c * 8];
#pragma unroll
    for (int i = 0; i < 8; ++i) acc[i] = fmaf((float)v[i], e.y, acc[i]);
  }

  // reduce across edge slots
#pragma unroll
  for (int d = LPE; d < 64; d <<= 1)
#pragma unroll
    for (int i = 0; i < 8; ++i) acc[i] += __shfl_xor(acc[i], d);

  if (lane < LPE) {
    const float4 b0 = *(const float4*)&bias[c * 8];
    const float4 b1 = *(const float4*)&bias[c * 8 + 4];
    float4 r0, r1;
    r0.x = fmaxf(acc[0] + b0.x, 0.f);
    r0.y = fmaxf(acc[1] + b0.y, 0.f);
    r0.z = fmaxf(acc[2] + b0.z, 0.f);
    r0.w = fmaxf(acc[3] + b0.w, 0.f);
    r1.x = fmaxf(acc[4] + b1.x, 0.f);
    r1.y = fmaxf(acc[5] + b1.y, 0.f);
    r1.z = fmaxf(acc[6] + b1.z, 0.f);
    r1.w = fmaxf(acc[7] + b1.w, 0.f);
    *(float4*)&outp[(size_t)n * F + c * 8] = r0;
    *(float4*)&outp[(size_t)n * F + c * 8 + 4] = r1;
  }
}

// ---------------- launch ----------------

extern "C" void kernel_launch(void* const* d_in, const int* in_sizes, int n_in,
                              void* d_out, int out_size, void* d_ws, size_t ws_size,
                              hipStream_t stream) {
  const float* x  = (const float*)d_in[0];
  const int*   ei = (const int*)d_in[1];
  const float* W1 = (const float*)d_in[2];
  const float* b1 = (const float*)d_in[3];
  const float* W2 = (const float*)d_in[4];
  const float* b2 = (const float*)d_in[5];
  float* out = (float*)d_out;

  const int F1 = in_sizes[3];           // 128
  const int F2 = in_sizes[5];           // 64
  const int F0 = in_sizes[2] / F1;      // 512
  const int N  = in_sizes[0] / F0;      // 100000
  const int E  = in_sizes[1] / 2;       // 1600000

  char* ws = (char*)d_ws;
  size_t off = 0;
  auto alloc = [&](size_t bytes) -> void* {
    void* p = ws + off;
    off = (off + bytes + 255) & ~(size_t)255;
    return p;
  };

  int*    cnt      = (int*)alloc((size_t)N * 4);
  int*    fillc    = (int*)alloc((size_t)N * 4);
  int*    rowstart = (int*)alloc((size_t)N * 4);
  float*  dinv     = (float*)alloc((size_t)N * 4);
  const int nb     = (N + SCAN_B - 1) / SCAN_B;
  int*    bsum     = (int*)alloc((size_t)nb * 4);
  float2* ew       = (float2*)alloc(((size_t)E + N) * 8);
  _Float16* h      = (_Float16*)alloc((size_t)N * F1 * 2);  // fp16 GEMM1 out
  float*  h1       = (float*)alloc((size_t)N * F1 * 4);     // fp32 agg1 out
  _Float16* h2     = h;  // fp16 GEMM2 out, reuses h (dead after agg1)
  unsigned short* W1h = (unsigned short*)alloc((size_t)F0 * F1 * 2);
  unsigned short* W1l = (unsigned short*)alloc((size_t)F0 * F1 * 2);
  unsigned short* W2h = (unsigned short*)alloc((size_t)F1 * F2 * 2);
  unsigned short* W2l = (unsigned short*)alloc((size_t)F1 * F2 * 2);

  zero2_kernel<<<(N + 255) / 256, 256, 0, stream>>>(cnt, fillc, N);
  count_kernel<<<(E + 255) / 256, 256, 0, stream>>>(ei, cnt, E);
  scan1_kernel<<<nb, SCAN_B, 0, stream>>>(cnt, rowstart, bsum, dinv, N);
  scan2_kernel<<<1, SCAN_B, 0, stream>>>(bsum, nb);
  scan3_kernel<<<(N + 255) / 256, 256, 0, stream>>>(rowstart, bsum, N);
  fillself_kernel<<<(E + N + 255) / 256, 256, 0, stream>>>(ei, fillc, rowstart, cnt, dinv, ew, E, N);
  wsplit2_kernel<<<(F0 * F1 + F1 * F2 + 255) / 256, 256, 0, stream>>>(
      W1, W1h, W1l, F0, F1, W2, W2h, W2l, F1, F2);

  // layer 1: h = fp16(x@W1) ; h1 = relu(agg(h) + b1)  (fp32)
  gemm_mfma_kernel<128, 128, _Float16><<<(N + 127) / 128, 512, 0, stream>>>(x, W1h, W1l, h, N, F0);
  {
    const long blocks = ((long)N * 64 + 255) / 256;
    agg_kernel<128><<<(int)blocks, 256, 0, stream>>>(h, rowstart, cnt, ew, b1, h1, N);
  }

  // layer 2: h2 = fp16(h1@W2) ; out = relu(agg(h2) + b2)
  gemm_mfma_kernel<128, 64, _Float16><<<(N + 127) / 128, 512, 0, stream>>>(h1, W2h, W2l, h2, N, F1);
  {
    const long blocks = ((long)N * 64 + 255) / 256;
    agg_kernel<64><<<(int)blocks, 256, 0, stream>>>(h2, rowstart, cnt, ew, b2, out, N);
  }
}

// Round 10
// 358.353 us; speedup vs baseline: 1.5866x; 1.0458x over previous
//
#include <hip/hip_runtime.h>

#define SCAN_B 1024

using f16x8 = __attribute__((ext_vector_type(8))) _Float16;
using f32x4 = __attribute__((ext_vector_type(4))) float;
typedef _Float16 half4v __attribute__((ext_vector_type(4)));
typedef _Float16 half8v __attribute__((ext_vector_type(8)));

// ---------------- precompute kernels ----------------

__global__ void zero2_kernel(int* __restrict__ a, int* __restrict__ b, int n) {
  int i = blockIdx.x * blockDim.x + threadIdx.x;
  if (i < n) { a[i] = 0; b[i] = 0; }
}

__global__ void count_kernel(const int* __restrict__ ei, int* __restrict__ cnt, int E) {
  int i = blockIdx.x * blockDim.x + threadIdx.x;
  if (i < E) atomicAdd(&cnt[ei[E + i]], 1);
}

// scan over (cnt[i] + 1) (row length incl. self edge); also emits dinv = rsqrt(deg)
__global__ void scan1_kernel(const int* __restrict__ cnt, int* __restrict__ rowstart,
                             int* __restrict__ bsum, float* __restrict__ dinv, int n) {
  __shared__ int sm[SCAN_B];
  const int t = threadIdx.x;
  const int i = blockIdx.x * SCAN_B + t;
  int c = (i < n) ? cnt[i] : 0;
  if (i < n) dinv[i] = rsqrtf((float)(c + 1));
  int v = (i < n) ? (c + 1) : 0;
  sm[t] = v;
  __syncthreads();
  for (int off = 1; off < SCAN_B; off <<= 1) {
    int x = (t >= off) ? sm[t - off] : 0;
    __syncthreads();
    if (t >= off) sm[t] += x;
    __syncthreads();
  }
  if (i < n) rowstart[i] = sm[t] - v;
  if (t == SCAN_B - 1) bsum[blockIdx.x] = sm[t];
}

__global__ void scan2_kernel(int* __restrict__ bsum, int nb) {
  __shared__ int sm[SCAN_B];
  const int t = threadIdx.x;
  int v = (t < nb) ? bsum[t] : 0;
  sm[t] = v;
  __syncthreads();
  for (int off = 1; off < SCAN_B; off <<= 1) {
    int x = (t >= off) ? sm[t - off] : 0;
    __syncthreads();
    if (t >= off) sm[t] += x;
    __syncthreads();
  }
  if (t < nb) bsum[t] = sm[t] - v;
}

__global__ void scan3_kernel(int* __restrict__ rowstart, const int* __restrict__ bsum, int n) {
  int i = blockIdx.x * blockDim.x + threadIdx.x;
  if (i < n) rowstart[i] += bsum[i / SCAN_B];
}

// fused: real edges (i < E) + self edges (i >= E, n = i - E, last slot of row n)
__global__ void fillself_kernel(const int* __restrict__ ei, int* __restrict__ fillc,
                                const int* __restrict__ rowstart, const int* __restrict__ cnt,
                                const float* __restrict__ dinv, float2* __restrict__ ew,
                                int E, int N) {
  int i = blockIdx.x * blockDim.x + threadIdx.x;
  if (i < E) {
    int s = ei[i];
    int d = ei[E + i];
    int p = atomicAdd(&fillc[d], 1);
    ew[rowstart[d] + p] = make_float2(__int_as_float(s), dinv[s] * dinv[d]);
  } else if (i < E + N) {
    int n = i - E;
    float dn = dinv[n];
    ew[rowstart[n] + cnt[n]] = make_float2(__int_as_float(n), dn * dn);
  }
}

// both weights in one launch: W [K][N] fp32 -> transposed [N][K] fp16 (RNE)
__global__ void wconv2_kernel(const float* __restrict__ W1, _Float16* __restrict__ W1t, int K1, int N1,
                              const float* __restrict__ W2, _Float16* __restrict__ W2t, int K2, int N2) {
  int i = blockIdx.x * blockDim.x + threadIdx.x;
  const int n1 = K1 * N1;
  if (i < n1) {
    int k = i / N1, n = i % N1;
    W1t[(size_t)n * K1 + k] = (_Float16)W1[i];
  } else if (i < n1 + K2 * N2) {
    int j = i - n1;
    int k = j / N2, n = j % N2;
    W2t[(size_t)n * K2 + k] = (_Float16)W2[j];
  }
}

// ---------------- fp16 MFMA GEMM, 8-wave, reg-prefetch ----------------
// C[M x N] = A[M x K] @ B[K x N], BN == N. 512 threads = 8 waves (2 x 4).
// A fp32 -> fp16 cvt in-kernel -> LDS; B pre-transposed Wt [N][K] fp16 -> LDS.
// Single f16 MFMA per fragment pair (error ~2^-11 per input, fp32 accumulate).
// Next tile's global loads issued after staging, drain under the MFMAs.

template <int BM, int BN, typename CT>
__global__ void __launch_bounds__(512, 2)
gemm_mfma_kernel(const float* __restrict__ A, const _Float16* __restrict__ Wt,
                 CT* __restrict__ C, int M, int K) {
  constexpr int BK   = 32;
  constexpr int LDK  = 40;                 // fp16 elems per LDS row (80B)
  constexpr int MR   = BM / 2 / 16;        // 4
  constexpr int NR   = BN / 4 / 16;        // 2 (BN=128) or 1 (BN=64)
  constexpr int N    = BN;
  constexpr int LDC  = NR * 16 + 4;        // epilogue patch row stride (floats)
  constexpr int SMA  = (BM + BN) * LDK * 2;
  constexpr int SME  = 8 * 16 * LDC * 4;
  constexpr int SMEM = SMA > SME ? SMA : SME;

  __shared__ __align__(16) char smem[SMEM];
  _Float16* Asm = (_Float16*)smem;
  _Float16* Bsm = Asm + (size_t)BM * LDK;

  const int tid  = threadIdx.x;
  const int lane = tid & 63;
  const int w    = tid >> 6;          // 0..7
  const int wm   = w >> 2;            // 0..1 (64 rows each)
  const int wn   = w & 3;             // 0..3
  const int fr   = lane & 15;
  const int fq   = lane >> 4;
  const int m0   = blockIdx.x * BM;

  const int a_c = tid & 7;            // k-chunk (4 elems)
  const int a_m = tid >> 3;           // row 0..63
  const int br  = tid >> 2;           // B row 0..127
  const int bj  = tid & 3;            // B 16B chunk (8 fp16)

  float4 av[2];
  uint4  bt;

  auto loadA = [&](int kt) {
#pragma unroll
    for (int p = 0; p < 2; ++p) {
      const int gm = m0 + a_m + 64 * p;
      av[p] = (gm < M) ? *(const float4*)&A[(size_t)gm * K + kt + 4 * a_c]
                       : make_float4(0.f, 0.f, 0.f, 0.f);
    }
  };
  auto loadB = [&](int kt) {
    if (tid < BN * 4) bt = *(const uint4*)&Wt[(size_t)br * K + kt + 8 * bj];
  };

  f32x4 acc[MR][NR] = {};

  loadA(0);
  loadB(0);

  for (int kt = 0; kt < K; kt += BK) {
    __syncthreads();   // previous tile's LDS frag reads complete

    // ---- A cvt + store; B copy ----
#pragma unroll
    for (int p = 0; p < 2; ++p) {
      const int r = a_m + 64 * p;
      half4v hv = {(_Float16)av[p].x, (_Float16)av[p].y, (_Float16)av[p].z, (_Float16)av[p].w};
      *(half4v*)((char*)Asm + r * (LDK * 2) + a_c * 8) = hv;
    }
    if (tid < BN * 4) *(uint4*)((char*)Bsm + br * (LDK * 2) + 16 * bj) = bt;
    __syncthreads();

    // ---- issue next tile's loads; they drain under the MFMA section ----
    if (kt + BK < K) {
      loadA(kt + BK);
      loadB(kt + BK);
    }

    // ---- fragments + MFMA ----
    f16x8 bfrag[NR];
#pragma unroll
    for (int ni = 0; ni < NR; ++ni) {
      const int r = wn * (NR * 16) + ni * 16 + fr;
      bfrag[ni] = *(const f16x8*)((const char*)Bsm + r * (LDK * 2) + fq * 16);
    }
#pragma unroll
    for (int mi = 0; mi < MR; ++mi) {
      const int r = wm * 64 + mi * 16 + fr;
      f16x8 afrag = *(const f16x8*)((const char*)Asm + r * (LDK * 2) + fq * 16);
#pragma unroll
      for (int ni = 0; ni < NR; ++ni)
        acc[mi][ni] = __builtin_amdgcn_mfma_f32_16x16x32_f16(afrag, bfrag[ni], acc[mi][ni], 0, 0, 0);
    }
  }

  // ---- epilogue: per-wave LDS patch -> coalesced stores ----
  __syncthreads();   // all frag reads done; smem reused
  {
    float* cst = (float*)smem + (size_t)w * (16 * LDC);
    constexpr int CPR   = NR * 4;        // float4 chunks per patch row
    constexpr int EPASS = (16 * CPR + 63) / 64;
#pragma unroll
    for (int mi = 0; mi < MR; ++mi) {
#pragma unroll
      for (int ni = 0; ni < NR; ++ni)
#pragma unroll
        for (int r = 0; r < 4; ++r)
          cst[(fq * 4 + r) * LDC + ni * 16 + fr] = acc[mi][ni][r];
#pragma unroll
      for (int p = 0; p < EPASS; ++p) {
        const int idx = p * 64 + lane;
        if (idx < 16 * CPR) {
          const int row = idx / CPR;
          const int ch  = idx % CPR;
          const int gm  = m0 + wm * 64 + mi * 16 + row;
          float4 v = *(const float4*)&cst[row * LDC + ch * 4];
          if (gm < M) {
            if constexpr (sizeof(CT) == 2) {
              half4v hv = {(_Float16)v.x, (_Float16)v.y, (_Float16)v.z, (_Float16)v.w};
              *(half4v*)&C[(size_t)gm * N + wn * (NR * 16) + ch * 4] = hv;
            } else {
              *(float4*)&C[(size_t)gm * N + wn * (NR * 16) + ch * 4] = v;
            }
          }
        }
      }
    }
  }
}

// ---------------- CSR pull aggregation over fp16 rows ----------------
// Lane loads 8 halfs (16B). F=128: 16 lanes/edge, 4 slots/wave; F=64: 8 lanes/edge, 8 slots.
// Unroll x4 -> up to 16 edges in flight per wave. fp32 accumulate, fp32 output.

template <int F>
__global__ void agg_kernel(const _Float16* __restrict__ hin, const int* __restrict__ rowstart,
                           const int* __restrict__ cnt, const float2* __restrict__ ew,
                           const float* __restrict__ bias, float* __restrict__ outp, int N) {
  constexpr int LPE = F / 8;    // lanes per edge
  constexpr int EPW = 64 / LPE; // edge slots per wave
  const int wave = (int)((blockIdx.x * (size_t)blockDim.x + threadIdx.x) >> 6);
  if (wave >= N) return;
  const int lane = threadIdx.x & 63;
  const int sub  = lane / LPE;
  const int c    = lane % LPE;
  const int n    = wave;

  const int beg = rowstart[n];
  const int end = beg + cnt[n] + 1;   // incl. self edge

  float acc[8] = {};
  int j = beg + sub;
  for (; j + 3 * EPW < end; j += 4 * EPW) {
    const float2 e0 = ew[j];
    const float2 e1 = ew[j + EPW];
    const float2 e2 = ew[j + 2 * EPW];
    const float2 e3 = ew[j + 3 * EPW];
    const half8v v0 = *(const half8v*)&hin[(size_t)__float_as_int(e0.x) * F + c * 8];
    const half8v v1 = *(const half8v*)&hin[(size_t)__float_as_int(e1.x) * F + c * 8];
    const half8v v2 = *(const half8v*)&hin[(size_t)__float_as_int(e2.x) * F + c * 8];
    const half8v v3 = *(const half8v*)&hin[(size_t)__float_as_int(e3.x) * F + c * 8];
#pragma unroll
    for (int i = 0; i < 8; ++i) {
      acc[i] = fmaf((float)v0[i], e0.y, acc[i]);
      acc[i] = fmaf((float)v1[i], e1.y, acc[i]);
      acc[i] = fmaf((float)v2[i], e2.y, acc[i]);
      acc[i] = fmaf((float)v3[i], e3.y, acc[i]);
    }
  }
  for (; j < end; j += EPW) {
    const float2 e = ew[j];
    const half8v v = *(const half8v*)&hin[(size_t)__float_as_int(e.x) * F + c * 8];
#pragma unroll
    for (int i = 0; i < 8; ++i) acc[i] = fmaf((float)v[i], e.y, acc[i]);
  }

  // reduce across edge slots
#pragma unroll
  for (int d = LPE; d < 64; d <<= 1)
#pragma unroll
    for (int i = 0; i < 8; ++i) acc[i] += __shfl_xor(acc[i], d);

  if (lane < LPE) {
    const float4 b0 = *(const float4*)&bias[c * 8];
    const float4 b1 = *(const float4*)&bias[c * 8 + 4];
    float4 r0, r1;
    r0.x = fmaxf(acc[0] + b0.x, 0.f);
    r0.y = fmaxf(acc[1] + b0.y, 0.f);
    r0.z = fmaxf(acc[2] + b0.z, 0.f);
    r0.w = fmaxf(acc[3] + b0.w, 0.f);
    r1.x = fmaxf(acc[4] + b1.x, 0.f);
    r1.y = fmaxf(acc[5] + b1.y, 0.f);
    r1.z = fmaxf(acc[6] + b1.z, 0.f);
    r1.w = fmaxf(acc[7] + b1.w, 0.f);
    *(float4*)&outp[(size_t)n * F + c * 8] = r0;
    *(float4*)&outp[(size_t)n * F + c * 8 + 4] = r1;
  }
}

// ---------------- launch ----------------

extern "C" void kernel_launch(void* const* d_in, const int* in_sizes, int n_in,
                              void* d_out, int out_size, void* d_ws, size_t ws_size,
                              hipStream_t stream) {
  const float* x  = (const float*)d_in[0];
  const int*   ei = (const int*)d_in[1];
  const float* W1 = (const float*)d_in[2];
  const float* b1 = (const float*)d_in[3];
  const float* W2 = (const float*)d_in[4];
  const float* b2 = (const float*)d_in[5];
  float* out = (float*)d_out;

  const int F1 = in_sizes[3];           // 128
  const int F2 = in_sizes[5];           // 64
  const int F0 = in_sizes[2] / F1;      // 512
  const int N  = in_sizes[0] / F0;      // 100000
  const int E  = in_sizes[1] / 2;       // 1600000

  char* ws = (char*)d_ws;
  size_t off = 0;
  auto alloc = [&](size_t bytes) -> void* {
    void* p = ws + off;
    off = (off + bytes + 255) & ~(size_t)255;
    return p;
  };

  int*    cnt      = (int*)alloc((size_t)N * 4);
  int*    fillc    = (int*)alloc((size_t)N * 4);
  int*    rowstart = (int*)alloc((size_t)N * 4);
  float*  dinv     = (float*)alloc((size_t)N * 4);
  const int nb     = (N + SCAN_B - 1) / SCAN_B;
  int*    bsum     = (int*)alloc((size_t)nb * 4);
  float2* ew       = (float2*)alloc(((size_t)E + N) * 8);
  _Float16* h      = (_Float16*)alloc((size_t)N * F1 * 2);  // fp16 GEMM1 out
  float*  h1       = (float*)alloc((size_t)N * F1 * 4);     // fp32 agg1 out
  _Float16* h2     = h;  // fp16 GEMM2 out, reuses h (dead after agg1)
  _Float16* W1t    = (_Float16*)alloc((size_t)F0 * F1 * 2);
  _Float16* W2t    = (_Float16*)alloc((size_t)F1 * F2 * 2);

  zero2_kernel<<<(N + 255) / 256, 256, 0, stream>>>(cnt, fillc, N);
  count_kernel<<<(E + 255) / 256, 256, 0, stream>>>(ei, cnt, E);
  scan1_kernel<<<nb, SCAN_B, 0, stream>>>(cnt, rowstart, bsum, dinv, N);
  scan2_kernel<<<1, SCAN_B, 0, stream>>>(bsum, nb);
  scan3_kernel<<<(N + 255) / 256, 256, 0, stream>>>(rowstart, bsum, N);
  fillself_kernel<<<(E + N + 255) / 256, 256, 0, stream>>>(ei, fillc, rowstart, cnt, dinv, ew, E, N);
  wconv2_kernel<<<(F0 * F1 + F1 * F2 + 255) / 256, 256, 0, stream>>>(
      W1, W1t, F0, F1, W2, W2t, F1, F2);

  // layer 1: h = fp16(x@W1) ; h1 = relu(agg(h) + b1)  (fp32)
  gemm_mfma_kernel<128, 128, _Float16><<<(N + 127) / 128, 512, 0, stream>>>(x, W1t, h, N, F0);
  {
    const long blocks = ((long)N * 64 + 255) / 256;
    agg_kernel<128><<<(int)blocks, 256, 0, stream>>>(h, rowstart, cnt, ew, b1, h1, N);
  }

  // layer 2: h2 = fp16(h1@W2) ; out = relu(agg(h2) + b2)
  gemm_mfma_kernel<128, 64, _Float16><<<(N + 127) / 128, 512, 0, stream>>>(h1, W2t, h2, N, F1);
  {
    const long blocks = ((long)N * 64 + 255) / 256;
    agg_kernel<64><<<(int)blocks, 256, 0, stream>>>(h2, rowstart, cnt, ew, b2, out, N);
  }
}